// Round 8
// baseline (7393.155 us; speedup 1.0000x reference)
//
#include <hip/hip_runtime.h>
#include <math.h>

#define ACT_NONE 0
#define ACT_GELU 1
#define ACT_SOFTPLUS 2

template<int ACT>
__device__ __forceinline__ float act_apply(float x){
  if (ACT == ACT_GELU)     return 0.5f * x * (1.0f + erff(x * 0.70710678118654752f));
  if (ACT == ACT_SOFTPLUS) return fmaxf(x, 0.0f) + log1pf(expf(-fabsf(x)));
  return x;
}

// ---------------- bf16 split helpers ----------------
__device__ __forceinline__ unsigned short f2bf(float x){
  unsigned u = __float_as_uint(x);
  u = u + 0x7FFFu + ((u >> 16) & 1u);
  return (unsigned short)(u >> 16);
}
__device__ __forceinline__ float bf2f(unsigned short b){
  return __uint_as_float(((unsigned)b) << 16);
}
__device__ __forceinline__ void bfsplit(float x, unsigned short &hi, unsigned short &lo){
  hi = f2bf(x);
  lo = f2bf(x - bf2f(hi));
}

typedef __attribute__((ext_vector_type(8))) short v8s;
typedef __attribute__((ext_vector_type(4))) float v4f;

// ---------------- bf16x2 MFMA GEMM: 128x128 tile, 256 thr (4 waves) ------------
// A [M][K] bf16 hi/lo; B TRANSPOSED [N][K] bf16 hi/lo.
// OUT: 0 = fp32 store (+bias), 2 = bf16-split store.
// R7: software-pipelined staging — prefetch k+32 into regs during compute of k.
template<int ACT, int OUT>
__global__ __launch_bounds__(256) void gemm_bf16x2_kernel(
    const unsigned short* __restrict__ Ahi, const unsigned short* __restrict__ Alo,
    const unsigned short* __restrict__ Bhi, const unsigned short* __restrict__ Blo,
    const float* __restrict__ bias, float* __restrict__ C,
    unsigned short* __restrict__ Chi, unsigned short* __restrict__ Clo,
    int K, int lda, int ldb, int ldc)
{
  __shared__ unsigned short As[2][128][40];
  __shared__ unsigned short Bs[2][128][40];
  const int tid = threadIdx.x;
  const int m0 = blockIdx.y * 128;
  const int n0 = blockIdx.x * 128;
  const int w = tid >> 6, lane = tid & 63;
  const int wm = (w & 1) * 64, wn = (w >> 1) * 64;
  const int fm = lane & 15, fq = lane >> 4;
  const int r = tid >> 1, h = tid & 1;

  const unsigned short* pAh = Ahi + (size_t)(m0 + r) * lda + h * 16;
  const unsigned short* pAl = Alo + (size_t)(m0 + r) * lda + h * 16;
  const unsigned short* pBh = Bhi + (size_t)(n0 + r) * ldb + h * 16;
  const unsigned short* pBl = Blo + (size_t)(n0 + r) * ldb + h * 16;

  v4f acc[4][4];
#pragma unroll
  for (int i = 0; i < 4; i++)
#pragma unroll
    for (int j = 0; j < 4; j++) acc[i][j] = (v4f){0.f, 0.f, 0.f, 0.f};

  // prologue: load k0 = 0
  uint4 ah0 = *(const uint4*)(pAh),     ah1 = *(const uint4*)(pAh + 8);
  uint4 al0 = *(const uint4*)(pAl),     al1 = *(const uint4*)(pAl + 8);
  uint4 bh0 = *(const uint4*)(pBh),     bh1 = *(const uint4*)(pBh + 8);
  uint4 bl0 = *(const uint4*)(pBl),     bl1 = *(const uint4*)(pBl + 8);

  for (int k0 = 0; k0 < K; k0 += 32) {
    __syncthreads();
    *(uint4*)&As[0][r][h * 16]     = ah0;
    *(uint4*)&As[0][r][h * 16 + 8] = ah1;
    *(uint4*)&As[1][r][h * 16]     = al0;
    *(uint4*)&As[1][r][h * 16 + 8] = al1;
    *(uint4*)&Bs[0][r][h * 16]     = bh0;
    *(uint4*)&Bs[0][r][h * 16 + 8] = bh1;
    *(uint4*)&Bs[1][r][h * 16]     = bl0;
    *(uint4*)&Bs[1][r][h * 16 + 8] = bl1;
    __syncthreads();

    if (k0 + 32 < K) {   // prefetch next K-step; overlaps with MFMA below
      int kn = k0 + 32;
      ah0 = *(const uint4*)(pAh + kn); ah1 = *(const uint4*)(pAh + kn + 8);
      al0 = *(const uint4*)(pAl + kn); al1 = *(const uint4*)(pAl + kn + 8);
      bh0 = *(const uint4*)(pBh + kn); bh1 = *(const uint4*)(pBh + kn + 8);
      bl0 = *(const uint4*)(pBl + kn); bl1 = *(const uint4*)(pBl + kn + 8);
    }

    v8s ah[4], al[4];
#pragma unroll
    for (int i = 0; i < 4; i++) {
      ah[i] = *(const v8s*)&As[0][wm + i * 16 + fm][fq * 8];
      al[i] = *(const v8s*)&As[1][wm + i * 16 + fm][fq * 8];
    }
#pragma unroll
    for (int j = 0; j < 4; j++) {
      v8s bh = *(const v8s*)&Bs[0][wn + j * 16 + fm][fq * 8];
      v8s bl = *(const v8s*)&Bs[1][wn + j * 16 + fm][fq * 8];
#pragma unroll
      for (int i = 0; i < 4; i++) {
        acc[i][j] = __builtin_amdgcn_mfma_f32_16x16x32_bf16(ah[i], bh, acc[i][j], 0, 0, 0);
        acc[i][j] = __builtin_amdgcn_mfma_f32_16x16x32_bf16(ah[i], bl, acc[i][j], 0, 0, 0);
        acc[i][j] = __builtin_amdgcn_mfma_f32_16x16x32_bf16(al[i], bh, acc[i][j], 0, 0, 0);
      }
    }
  }

#pragma unroll
  for (int i = 0; i < 4; i++)
#pragma unroll
    for (int j = 0; j < 4; j++) {
      int col = n0 + wn + j * 16 + fm;
      float bv = bias ? bias[col] : 0.0f;
#pragma unroll
      for (int reg = 0; reg < 4; reg++) {
        int row = m0 + wm + i * 16 + fq * 4 + reg;
        float v = acc[i][j][reg] + bv;
        v = act_apply<ACT>(v);
        size_t idx = (size_t)row * ldc + col;
        if (OUT == 0) C[idx] = v;
        else { unsigned short hi, lo; bfsplit(v, hi, lo); Chi[idx] = hi; Clo[idx] = lo; }
      }
    }
}

// ------- fused GEMM(bf16x2) + residual + LayerNorm + split write ---------------
// tile 32 rows x 256 cols, 256 thr. X <- LN(X + A@B + bias)*g + beta (in-place).
// R7: pipelined staging like gemm_bf16x2.
__global__ __launch_bounds__(256) void gemm_ln_kernel(
    const unsigned short* __restrict__ Ahi, const unsigned short* __restrict__ Alo,
    const unsigned short* __restrict__ Bhi, const unsigned short* __restrict__ Blo,
    const float* __restrict__ bias,
    const float* __restrict__ g, const float* __restrict__ beta,
    unsigned short* __restrict__ Xhi, unsigned short* __restrict__ Xlo,
    int K, int lda, int ldb)
{
  __shared__ unsigned short As[2][32][40];
  __shared__ unsigned short Bs[2][256][40];
  __shared__ float rs[32][5];
  __shared__ float ms[32][2];
  const int tid = threadIdx.x;
  const int m0 = blockIdx.x * 32;
  const int w = tid >> 6, lane = tid & 63;
  const int fm = lane & 15, fq = lane >> 4;
  const int a_sel = tid >> 7;
  const int a_row = (tid >> 2) & 31;
  const int a_c   = tid & 3;
  const int b_row = tid >> 2;
  const int b_c   = tid & 3;

  const unsigned short* pA = (a_sel ? Alo : Ahi) + (size_t)(m0 + a_row) * lda + a_c * 8;

  v4f acc[2][4];
#pragma unroll
  for (int i = 0; i < 2; i++)
#pragma unroll
    for (int j = 0; j < 4; j++) acc[i][j] = (v4f){0.f, 0.f, 0.f, 0.f};

  // prologue loads (k0 = 0)
  uint4 av = *(const uint4*)pA;
  uint4 bvh[4], bvl[4];
#pragma unroll
  for (int p = 0; p < 4; p++) {
    int row = p * 64 + b_row;
    bvh[p] = *(const uint4*)(Bhi + (size_t)row * ldb + b_c * 8);
    bvl[p] = *(const uint4*)(Blo + (size_t)row * ldb + b_c * 8);
  }

  for (int k0 = 0; k0 < K; k0 += 32) {
    __syncthreads();
    *(uint4*)&As[a_sel][a_row][a_c * 8] = av;
#pragma unroll
    for (int p = 0; p < 4; p++) {
      int row = p * 64 + b_row;
      *(uint4*)&Bs[0][row][b_c * 8] = bvh[p];
      *(uint4*)&Bs[1][row][b_c * 8] = bvl[p];
    }
    __syncthreads();

    if (k0 + 32 < K) {
      int kn = k0 + 32;
      av = *(const uint4*)(pA + kn);
#pragma unroll
      for (int p = 0; p < 4; p++) {
        int row = p * 64 + b_row;
        bvh[p] = *(const uint4*)(Bhi + (size_t)row * ldb + kn + b_c * 8);
        bvl[p] = *(const uint4*)(Blo + (size_t)row * ldb + kn + b_c * 8);
      }
    }

    v8s ah[2], al[2];
#pragma unroll
    for (int i = 0; i < 2; i++) {
      ah[i] = *(const v8s*)&As[0][i * 16 + fm][fq * 8];
      al[i] = *(const v8s*)&As[1][i * 16 + fm][fq * 8];
    }
#pragma unroll
    for (int j = 0; j < 4; j++) {
      v8s bhf = *(const v8s*)&Bs[0][w * 64 + j * 16 + fm][fq * 8];
      v8s blf = *(const v8s*)&Bs[1][w * 64 + j * 16 + fm][fq * 8];
#pragma unroll
      for (int i = 0; i < 2; i++) {
        acc[i][j] = __builtin_amdgcn_mfma_f32_16x16x32_bf16(ah[i], bhf, acc[i][j], 0, 0, 0);
        acc[i][j] = __builtin_amdgcn_mfma_f32_16x16x32_bf16(ah[i], blf, acc[i][j], 0, 0, 0);
        acc[i][j] = __builtin_amdgcn_mfma_f32_16x16x32_bf16(al[i], bhf, acc[i][j], 0, 0, 0);
      }
    }
  }

  // acc <- x_old + delta + bias
#pragma unroll
  for (int i = 0; i < 2; i++)
#pragma unroll
    for (int j = 0; j < 4; j++) {
      int cl = w * 64 + j * 16 + fm;
      float bv = bias[cl];
#pragma unroll
      for (int reg = 0; reg < 4; reg++) {
        int rl = i * 16 + fq * 4 + reg;
        size_t idx = (size_t)(m0 + rl) * 256 + cl;
        acc[i][j][reg] += bv + bf2f(Xhi[idx]) + bf2f(Xlo[idx]);
      }
    }
  // mean
#pragma unroll
  for (int i = 0; i < 2; i++)
#pragma unroll
    for (int reg = 0; reg < 4; reg++) {
      float s = acc[i][0][reg] + acc[i][1][reg] + acc[i][2][reg] + acc[i][3][reg];
      s += __shfl_xor(s, 1); s += __shfl_xor(s, 2);
      s += __shfl_xor(s, 4); s += __shfl_xor(s, 8);
      if (fm == 0) rs[i * 16 + fq * 4 + reg][w] = s;
    }
  __syncthreads();
  if (tid < 32) ms[tid][0] = (rs[tid][0] + rs[tid][1] + rs[tid][2] + rs[tid][3]) * (1.0f / 256.0f);
  __syncthreads();
  // var
#pragma unroll
  for (int i = 0; i < 2; i++)
#pragma unroll
    for (int reg = 0; reg < 4; reg++) {
      int rl = i * 16 + fq * 4 + reg;
      float mean = ms[rl][0];
      float s = 0.0f;
#pragma unroll
      for (int j = 0; j < 4; j++) { float d = acc[i][j][reg] - mean; s += d * d; }
      s += __shfl_xor(s, 1); s += __shfl_xor(s, 2);
      s += __shfl_xor(s, 4); s += __shfl_xor(s, 8);
      if (fm == 0) rs[rl][w] = s;
    }
  __syncthreads();
  if (tid < 32) {
    float var = (rs[tid][0] + rs[tid][1] + rs[tid][2] + rs[tid][3]) * (1.0f / 256.0f);
    ms[tid][1] = rsqrtf(var + 1e-5f);
  }
  __syncthreads();
#pragma unroll
  for (int i = 0; i < 2; i++)
#pragma unroll
    for (int j = 0; j < 4; j++) {
      int cl = w * 64 + j * 16 + fm;
      float gv = g[cl], bv = beta[cl];
#pragma unroll
      for (int reg = 0; reg < 4; reg++) {
        int rl = i * 16 + fq * 4 + reg;
        float t = (acc[i][j][reg] - ms[rl][0]) * ms[rl][1] * gv + bv;
        size_t idx = (size_t)(m0 + rl) * 256 + cl;
        unsigned short hi, lo; bfsplit(t, hi, lo);
        Xhi[idx] = hi; Xlo[idx] = lo;
      }
    }
}

// -------- weight transpose + split (batched over layers via blockIdx.z) --------
__global__ __launch_bounds__(256) void wsplit_kernel(
    const float* __restrict__ W, unsigned short* __restrict__ Whi,
    unsigned short* __restrict__ Wlo, int K, int N, size_t wstride, size_t ostride)
{
  __shared__ float tile[32][33];
  const float* Wl = W + blockIdx.z * wstride;
  unsigned short* Whl = Whi + blockIdx.z * ostride;
  unsigned short* Wll = Wlo + blockIdx.z * ostride;
  int k0 = blockIdx.y * 32, n0 = blockIdx.x * 32;
  int t = threadIdx.x;
  int tn = t & 31, tk8 = t >> 5;
#pragma unroll
  for (int i = 0; i < 4; i++) {
    int k = tk8 + i * 8;
    tile[k][tn] = Wl[(size_t)(k0 + k) * N + n0 + tn];
  }
  __syncthreads();
  int tk = t & 31, tn8 = t >> 5;
#pragma unroll
  for (int i = 0; i < 4; i++) {
    int n = tn8 + i * 8;
    float v = tile[tk][n];
    unsigned short hi, lo; bfsplit(v, hi, lo);
    size_t idx = (size_t)(n0 + n) * K + k0 + tk;
    Whl[idx] = hi; Wll[idx] = lo;
  }
}

// ------------- fp32 GEMM 128x128 (embed only), POS + split write ---------------
template<int ACT, int POS, int SPLIT>
__global__ __launch_bounds__(256) void gemm128_kernel(
    const float* __restrict__ A, const float* __restrict__ W,
    const float* __restrict__ bias, const float* __restrict__ pos,
    float* __restrict__ C, unsigned short* __restrict__ Chi, unsigned short* __restrict__ Clo,
    int K, int lda, int ldw, int ldc)
{
  __shared__ float As[16][128];
  __shared__ float Ws[16][128];
  const int tid = threadIdx.x;
  const int m0 = blockIdx.y * 128;
  const int n0 = blockIdx.x * 128;
  const int tx = tid & 15, ty = tid >> 4;
  const int ar = tid >> 2, ak = (tid & 3) * 4;
  const int wk = tid >> 5, wn = (tid & 31) * 4;

  float acc[8][8];
#pragma unroll
  for (int i = 0; i < 8; i++)
#pragma unroll
    for (int j = 0; j < 8; j++) acc[i][j] = 0.0f;

  for (int k0 = 0; k0 < K; k0 += 16) {
    float4 a0 = *(const float4*)(A + (size_t)(m0 + ar)      * lda + k0 + ak);
    float4 a1 = *(const float4*)(A + (size_t)(m0 + ar + 64) * lda + k0 + ak);
    float4 w0 = *(const float4*)(W + (size_t)(k0 + wk)     * ldw + n0 + wn);
    float4 w1 = *(const float4*)(W + (size_t)(k0 + wk + 8) * ldw + n0 + wn);
    __syncthreads();
    As[ak + 0][ar] = a0.x; As[ak + 1][ar] = a0.y; As[ak + 2][ar] = a0.z; As[ak + 3][ar] = a0.w;
    As[ak + 0][ar + 64] = a1.x; As[ak + 1][ar + 64] = a1.y; As[ak + 2][ar + 64] = a1.z; As[ak + 3][ar + 64] = a1.w;
    *(float4*)&Ws[wk][wn] = w0;
    *(float4*)&Ws[wk + 8][wn] = w1;
    __syncthreads();
#pragma unroll
    for (int k = 0; k < 16; k++) {
      float4 xa = *(float4*)&As[k][ty * 8];
      float4 xb = *(float4*)&As[k][ty * 8 + 4];
      float4 y0 = *(float4*)&Ws[k][tx * 8];
      float4 y1 = *(float4*)&Ws[k][tx * 8 + 4];
      float a8[8] = {xa.x, xa.y, xa.z, xa.w, xb.x, xb.y, xb.z, xb.w};
      float b8[8] = {y0.x, y0.y, y0.z, y0.w, y1.x, y1.y, y1.z, y1.w};
#pragma unroll
      for (int i = 0; i < 8; i++)
#pragma unroll
        for (int j = 0; j < 8; j++) acc[i][j] = fmaf(a8[i], b8[j], acc[i][j]);
    }
  }
#pragma unroll
  for (int i = 0; i < 8; i++) {
    int row = m0 + ty * 8 + i;
    float* cp = C + (size_t)row * ldc + n0 + tx * 8;
    float v[8];
#pragma unroll
    for (int j = 0; j < 8; j++) {
      float t = acc[i][j];
      int col = n0 + tx * 8 + j;
      if (bias) t += bias[col];
      if (POS)  t += pos[(row & 63) * 256 + col];
      t = act_apply<ACT>(t);
      v[j] = t;
      if (SPLIT) {
        unsigned short hi, lo; bfsplit(t, hi, lo);
        size_t idx = (size_t)row * ldc + col;
        Chi[idx] = hi; Clo[idx] = lo;
      }
    }
    *(float4*)cp       = make_float4(v[0], v[1], v[2], v[3]);
    *(float4*)(cp + 4) = make_float4(v[4], v[5], v[6], v[7]);
  }
}

// ---------------- GEMM 64x64 tile fp32 (mamba), pipelined ----------------
template<int ACT>
__global__ __launch_bounds__(256) void gemm64_kernel(
    const float* __restrict__ A, const float* __restrict__ W,
    const float* __restrict__ bias, float* __restrict__ C,
    int K, int lda, int ldw, int ldc)
{
  __shared__ float As[16][64];
  __shared__ float Ws[16][64];
  const int tid = threadIdx.x;
  const int m0 = blockIdx.y * 64;
  const int n0 = blockIdx.x * 64;
  const int tx = tid & 15, ty = tid >> 4;
  const int ar = tid >> 2, ak = (tid & 3) * 4;
  const int wk = tid >> 4, wn = (tid & 15) * 4;

  float acc[4][4];
#pragma unroll
  for (int i = 0; i < 4; i++)
#pragma unroll
    for (int j = 0; j < 4; j++) acc[i][j] = 0.0f;

  float4 a0 = *(const float4*)(A + (size_t)(m0 + ar) * lda + ak);
  float4 w0 = *(const float4*)(W + (size_t)wk * ldw + n0 + wn);

  for (int k0 = 0; k0 < K; k0 += 16) {
    __syncthreads();
    As[ak + 0][ar] = a0.x; As[ak + 1][ar] = a0.y; As[ak + 2][ar] = a0.z; As[ak + 3][ar] = a0.w;
    *(float4*)&Ws[wk][wn] = w0;
    __syncthreads();
    if (k0 + 16 < K) {
      a0 = *(const float4*)(A + (size_t)(m0 + ar) * lda + k0 + 16 + ak);
      w0 = *(const float4*)(W + (size_t)(k0 + 16 + wk) * ldw + n0 + wn);
    }
#pragma unroll
    for (int k = 0; k < 16; k++) {
      float4 xa = *(float4*)&As[k][ty * 4];
      float4 yb = *(float4*)&Ws[k][tx * 4];
      float a4[4] = {xa.x, xa.y, xa.z, xa.w};
      float b4[4] = {yb.x, yb.y, yb.z, yb.w};
#pragma unroll
      for (int i = 0; i < 4; i++)
#pragma unroll
        for (int j = 0; j < 4; j++) acc[i][j] = fmaf(a4[i], b4[j], acc[i][j]);
    }
  }
#pragma unroll
  for (int i = 0; i < 4; i++) {
    float* cp = C + (size_t)(m0 + ty * 4 + i) * ldc + n0 + tx * 4;
    float v[4];
#pragma unroll
    for (int j = 0; j < 4; j++) {
      float t = acc[i][j];
      if (bias) t += bias[n0 + tx * 4 + j];
      v[j] = act_apply<ACT>(t);
    }
    *(float4*)cp = make_float4(v[0], v[1], v[2], v[3]);
  }
}

// ---------------- fused attention; writes bf16-split AT ----------------
__global__ __launch_bounds__(64) void attn_fused_kernel(
    const float* __restrict__ QKVc, const float* __restrict__ mask,
    unsigned short* __restrict__ AThi, unsigned short* __restrict__ ATlo, int n0)
{
  int bid = blockIdx.x;
  int nl = bid >> 3;
  int h = bid & 7;
  int n = n0 + nl;
  int tid = threadIdx.x;
  int tx = tid & 7, ty = tid >> 3;
  __shared__ float Qt[32][68];
  __shared__ float Kt[32][68];
  __shared__ float Vs[64][36];
  __shared__ float Pt[64][68];
  __shared__ float bs[64];
  const float* base = QKVc + (size_t)nl * (64 * 768);
#pragma unroll
  for (int i = 0; i < 32; i++) {
    int idx = tid + i * 64;
    int bar = idx >> 5, c = idx & 31;
    Qt[c][bar] = base[bar * 768 + h * 32 + c];
    Kt[c][bar] = base[bar * 768 + 256 + h * 32 + c];
    Vs[bar][c] = base[bar * 768 + 512 + h * 32 + c];
  }
  bs[tid] = (1.0f - mask[n * 64 + tid]) * -1e9f;
  __syncthreads();
  float acc[8][8] = {};
  for (int c = 0; c < 32; c++) {
    float4 ax = *(float4*)&Qt[c][ty * 8];
    float4 ay = *(float4*)&Qt[c][ty * 8 + 4];
    float4 bx = *(float4*)&Kt[c][tx * 8];
    float4 by = *(float4*)&Kt[c][tx * 8 + 4];
    float a8[8] = {ax.x, ax.y, ax.z, ax.w, ay.x, ay.y, ay.z, ay.w};
    float b8[8] = {bx.x, bx.y, bx.z, bx.w, by.x, by.y, by.z, by.w};
#pragma unroll
    for (int i = 0; i < 8; i++)
#pragma unroll
      for (int j = 0; j < 8; j++) acc[i][j] = fmaf(a8[i], b8[j], acc[i][j]);
  }
  const float scale = 0.17677669529663687f;
#pragma unroll
  for (int i = 0; i < 8; i++) {
    float s[8];
    float mx = -3.0e38f;
#pragma unroll
    for (int j = 0; j < 8; j++) { s[j] = acc[i][j] * scale + bs[tx * 8 + j]; mx = fmaxf(mx, s[j]); }
#pragma unroll
    for (int off = 1; off < 8; off <<= 1) mx = fmaxf(mx, __shfl_xor(mx, off));
    float sum = 0.0f;
#pragma unroll
    for (int j = 0; j < 8; j++) { s[j] = expf(s[j] - mx); sum += s[j]; }
#pragma unroll
    for (int off = 1; off < 8; off <<= 1) sum += __shfl_xor(sum, off);
    float inv = 1.0f / sum;
#pragma unroll
    for (int j = 0; j < 8; j++) Pt[tx * 8 + j][ty * 8 + i] = s[j] * inv;
  }
  __syncthreads();
  float o[8][4] = {};
  for (int j = 0; j < 64; j++) {
    float4 px = *(float4*)&Pt[j][ty * 8];
    float4 py = *(float4*)&Pt[j][ty * 8 + 4];
    float4 v  = *(float4*)&Vs[j][tx * 4];
    float p8[8] = {px.x, px.y, px.z, px.w, py.x, py.y, py.z, py.w};
#pragma unroll
    for (int i = 0; i < 8; i++) {
      o[i][0] = fmaf(p8[i], v.x, o[i][0]);
      o[i][1] = fmaf(p8[i], v.y, o[i][1]);
      o[i][2] = fmaf(p8[i], v.z, o[i][2]);
      o[i][3] = fmaf(p8[i], v.w, o[i][3]);
    }
  }
#pragma unroll
  for (int i = 0; i < 8; i++) {
    size_t base_o = (size_t)(nl * 64 + ty * 8 + i) * 256 + h * 32 + tx * 4;
#pragma unroll
    for (int c = 0; c < 4; c++) {
      unsigned short hi, lo; bfsplit(o[i][c], hi, lo);
      AThi[base_o + c] = hi; ATlo[base_o + c] = lo;
    }
  }
}

// ---------------- LayerNorm wave-per-row (mamba): o = LN(a)*g+beta + b ----------
__global__ __launch_bounds__(256) void ln_res_kernel(
    const float* __restrict__ a, const float* __restrict__ b,
    const float* __restrict__ g, const float* __restrict__ beta,
    float* __restrict__ o, int Wd)
{
  int wave = threadIdx.x >> 6;
  int lane = threadIdx.x & 63;
  int row = blockIdx.x * 4 + wave;
  int P = Wd >> 6;
  const float* ar = a + (size_t)row * Wd;
  const float* br = b + (size_t)row * Wd;
  float v[8];
  float s = 0.0f;
  for (int i = 0; i < P; i++) { float x = ar[lane + i * 64]; v[i] = x; s += x; }
#pragma unroll
  for (int off = 32; off; off >>= 1) s += __shfl_xor(s, off);
  float mean = s / Wd;
  float vs = 0.0f;
  for (int i = 0; i < P; i++) { float d = v[i] - mean; vs += d * d; }
#pragma unroll
  for (int off = 32; off; off >>= 1) vs += __shfl_xor(vs, off);
  float rstd = rsqrtf(vs / Wd + 1e-5f);
  for (int i = 0; i < P; i++) {
    int col = lane + i * 64;
    o[(size_t)row * Wd + col] = (v[i] - mean) * rstd * g[col] + beta[col] + br[col];
  }
}

// ------------- masked mean over bars (reads hi/lo X) ---------------------------
__global__ __launch_bounds__(256) void mean_kernel(
    const unsigned short* __restrict__ Xhi, const unsigned short* __restrict__ Xlo,
    const float* __restrict__ mask, float* __restrict__ FE, int n0)
{
  int n = blockIdx.x;
  int c = threadIdx.x;
  float s = 0.0f, ms = 0.0f;
  for (int bar = 0; bar < 64; bar++) {
    float mk = mask[(n0 + n) * 64 + bar];
    size_t idx = (size_t)(n * 64 + bar) * 256 + c;
    s = fmaf(bf2f(Xhi[idx]) + bf2f(Xlo[idx]), mk, s);
    ms += mk;
  }
  FE[(n0 + n) * 256 + c] = s / fmaxf(ms, 1.0f);
}

// ---------------- mamba conv (4-tap causal) + silu ----------------
__global__ __launch_bounds__(256) void conv_kernel(
    const float* __restrict__ XZ, const float* __restrict__ w,
    const float* __restrict__ b, float* __restrict__ XC)
{
  int idx = blockIdx.x * 256 + threadIdx.x;
  int t = idx >> 10, c = idx & 1023;
  float acc = b[c];
  const float* wc = w + c * 4;
#pragma unroll
  for (int k = 0; k < 4; k++) {
    int tt = t + k - 3;
    if (tt >= 0) acc = fmaf(XZ[(size_t)tt * 2048 + c], wc[k], acc);
  }
  XC[idx] = acc / (1.0f + expf(-acc));
}

// ---------------- chunked scan (32 chunks x 32 steps) ----------------
#define NCH 32
#define CLEN 32

__global__ __launch_bounds__(256) void scan1_kernel(
    const float* __restrict__ DT, const float* __restrict__ XC,
    const float* __restrict__ XDBL, const float* __restrict__ Alog,
    float* __restrict__ HEND, float* __restrict__ PPR)
{
  int j = blockIdx.x >> 2;
  int c = (blockIdx.x & 3) * 256 + threadIdx.x;
  int t0 = j * CLEN;
  __shared__ float Bs[CLEN][16];
  for (int i = threadIdx.x; i < CLEN * 16; i += 256) {
    int r = i >> 4, s = i & 15;
    Bs[r][s] = XDBL[(t0 + r) * 64 + 32 + s];
  }
  float A[16], h[16], Pp[16];
#pragma unroll
  for (int s = 0; s < 16; s++) {
    A[s] = -expf(Alog[c * 16 + s]);
    h[s] = 0.0f; Pp[s] = 1.0f;
  }
  __syncthreads();
  for (int tt = 0; tt < CLEN; tt++) {
    int t = t0 + tt;
    float dtv = DT[(size_t)t * 1024 + c];
    float u = dtv * XC[(size_t)t * 1024 + c];
#pragma unroll
    for (int s = 0; s < 16; s++) {
      float e = expf(dtv * A[s]);
      h[s] = fmaf(h[s], e, u * Bs[tt][s]);
      Pp[s] *= e;
    }
  }
#pragma unroll
  for (int s = 0; s < 16; s++) {
    HEND[(size_t)(j * 1024 + c) * 16 + s] = h[s];
    PPR [(size_t)(j * 1024 + c) * 16 + s] = Pp[s];
  }
}

__global__ __launch_bounds__(256) void scan2_kernel(
    const float* __restrict__ HEND, const float* __restrict__ PPR, float* __restrict__ CIN)
{
  int id = blockIdx.x * 256 + threadIdx.x;
  float carry = 0.0f;
  for (int j = 0; j < NCH; j++) {
    CIN[j * 16384 + id] = carry;
    carry = fmaf(PPR[j * 16384 + id], carry, HEND[j * 16384 + id]);
  }
}

__global__ __launch_bounds__(256) void scan3_kernel(
    const float* __restrict__ DT, const float* __restrict__ XC,
    const float* __restrict__ XDBL, const float* __restrict__ Alog,
    const float* __restrict__ CIN, const float* __restrict__ mD,
    const float* __restrict__ XZ, float* __restrict__ Y)
{
  int j = blockIdx.x >> 2;
  int c = (blockIdx.x & 3) * 256 + threadIdx.x;
  int t0 = j * CLEN;
  __shared__ float Bs[CLEN][16], Cs[CLEN][16];
  for (int i = threadIdx.x; i < CLEN * 16; i += 256) {
    int r = i >> 4, s = i & 15;
    Bs[r][s] = XDBL[(t0 + r) * 64 + 32 + s];
    Cs[r][s] = XDBL[(t0 + r) * 64 + 48 + s];
  }
  float A[16], h[16];
#pragma unroll
  for (int s = 0; s < 16; s++) {
    A[s] = -expf(Alog[c * 16 + s]);
    h[s] = CIN[(size_t)(j * 1024 + c) * 16 + s];
  }
  float dval = mD[c];
  __syncthreads();
  for (int tt = 0; tt < CLEN; tt++) {
    int t = t0 + tt;
    float dtv = DT[(size_t)t * 1024 + c];
    float xcv = XC[(size_t)t * 1024 + c];
    float u = dtv * xcv;
    float y = 0.0f;
#pragma unroll
    for (int s = 0; s < 16; s++) {
      float e = expf(dtv * A[s]);
      h[s] = fmaf(h[s], e, u * Bs[tt][s]);
      y = fmaf(h[s], Cs[tt][s], y);
    }
    float z = XZ[(size_t)t * 2048 + 1024 + c];
    float sz = z / (1.0f + expf(-z));
    Y[(size_t)t * 1024 + c] = (y + dval * xcv) * sz;
  }
}

// ---------------- pooling + head ----------------
__global__ __launch_bounds__(1024) void pool1_kernel(
    const float* __restrict__ XM, const float* __restrict__ pw,
    const float* __restrict__ pb, float* __restrict__ PW)
{
  int t = threadIdx.x;
  float s = pb[0];
  for (int i = 0; i < 512; i++) s = fmaf(XM[(size_t)t * 512 + i], pw[i], s);
  __shared__ float red[1024];
  red[t] = s;
  __syncthreads();
  for (int off = 512; off > 0; off >>= 1) {
    if (t < off) red[t] = fmaxf(red[t], red[t + off]);
    __syncthreads();
  }
  float mx = red[0];
  __syncthreads();
  float e = expf(s - mx);
  red[t] = e;
  __syncthreads();
  for (int off = 512; off > 0; off >>= 1) {
    if (t < off) red[t] = red[t] + red[t + off];
    __syncthreads();
  }
  PW[t] = e / red[0];
}

__global__ __launch_bounds__(256) void pool2_kernel(
    const float* __restrict__ XM, const float* __restrict__ PW, float* __restrict__ HP)
{
  int hcol = blockIdx.x * 256 + threadIdx.x;
  float s = 0.0f;
  for (int tn = 0; tn < 1024; tn++) s = fmaf(PW[tn], XM[(size_t)tn * 512 + hcol], s);
  HP[hcol] = s;
}

__device__ __forceinline__ float blk_reduce_sum_128(float v, float* red){
  int t = threadIdx.x;
#pragma unroll
  for (int off = 32; off; off >>= 1) v += __shfl_xor(v, off);
  __syncthreads();
  if ((t & 63) == 0) red[t >> 6] = v;
  __syncthreads();
  return red[0] + red[1];
}

__global__ __launch_bounds__(128) void head_kernel(
    const float* __restrict__ HP, const float* __restrict__ h1w, const float* __restrict__ h1b,
    const float* __restrict__ g1, const float* __restrict__ be1,
    const float* __restrict__ h2w, const float* __restrict__ h2b,
    const float* __restrict__ g2, const float* __restrict__ be2,
    const float* __restrict__ h3w, const float* __restrict__ h3b,
    float* __restrict__ out)
{
  __shared__ float t1[128];
  __shared__ float red[2];
  int i = threadIdx.x;
  float s = h1b[i];
  for (int k = 0; k < 512; k++) s = fmaf(HP[k], h1w[k * 128 + i], s);
  float mean = blk_reduce_sum_128(s, red) * (1.0f / 128.0f);
  float d = s - mean;
  float var = blk_reduce_sum_128(d * d, red) * (1.0f / 128.0f);
  float x1 = d * rsqrtf(var + 1e-5f) * g1[i] + be1[i];
  x1 = 0.5f * x1 * (1.0f + erff(x1 * 0.70710678118654752f));
  t1[i] = x1;
  __syncthreads();
  s = h2b[i];
  for (int k = 0; k < 128; k++) s = fmaf(t1[k], h2w[k * 128 + i], s);
  mean = blk_reduce_sum_128(s, red) * (1.0f / 128.0f);
  d = s - mean;
  var = blk_reduce_sum_128(d * d, red) * (1.0f / 128.0f);
  float x2 = d * rsqrtf(var + 1e-5f) * g2[i] + be2[i];
  x2 = 0.5f * x2 * (1.0f + erff(x2 * 0.70710678118654752f));
  float tot = blk_reduce_sum_128(x2 * h3w[i], red);
  if (i == 0) out[0] = tot + h3b[0];
}

__global__ __launch_bounds__(256) void copyx_kernel(const float* __restrict__ XM, float* __restrict__ out){
  int i = blockIdx.x * 256 + threadIdx.x;
  out[1 + i] = XM[i];
}

// ---------------- launch ----------------
extern "C" void kernel_launch(void* const* d_in, const int* in_sizes, int n_in,
                              void* d_out, int out_size, void* d_ws, size_t ws_size,
                              hipStream_t stream)
{
  const float* frames   = (const float*)d_in[0];
  const float* fmask    = (const float*)d_in[1];
  const float* in_w     = (const float*)d_in[2];
  const float* in_b     = (const float*)d_in[3];
  const float* pos_emb  = (const float*)d_in[4];
  const float* qkv_w    = (const float*)d_in[5];
  const float* qkv_b    = (const float*)d_in[6];
  const float* ao_w     = (const float*)d_in[7];
  const float* ao_b     = (const float*)d_in[8];
  const float* ln1_g    = (const float*)d_in[9];
  const float* ln1_b    = (const float*)d_in[10];
  const float* ffn_w1   = (const float*)d_in[11];
  const float* ffn_b1   = (const float*)d_in[12];
  const float* ffn_w2   = (const float*)d_in[13];
  const float* ffn_b2   = (const float*)d_in[14];
  const float* ln2_g    = (const float*)d_in[15];
  const float* ln2_b    = (const float*)d_in[16];
  const float* proj_w   = (const float*)d_in[17];
  const float* proj_b   = (const float*)d_in[18];
  const float* m_in_w   = (const float*)d_in[19];
  const float* m_conv_w = (const float*)d_in[20];
  const float* m_conv_b = (const float*)d_in[21];
  const float* m_xproj_w= (const float*)d_in[22];
  const float* m_dt_w   = (const float*)d_in[23];
  const float* m_dt_b   = (const float*)d_in[24];
  const float* m_Alog   = (const float*)d_in[25];
  const float* m_D      = (const float*)d_in[26];
  const float* m_out_w  = (const float*)d_in[27];
  const float* m_ln_g   = (const float*)d_in[28];
  const float* m_ln_b   = (const float*)d_in[29];
  const float* pool_w   = (const float*)d_in[30];
  const float* pool_b   = (const float*)d_in[31];
  const float* h1_w     = (const float*)d_in[32];
  const float* h1_b     = (const float*)d_in[33];
  const float* hg1      = (const float*)d_in[34];
  const float* hb1      = (const float*)d_in[35];
  const float* h2_w     = (const float*)d_in[36];
  const float* h2_b     = (const float*)d_in[37];
  const float* hg2      = (const float*)d_in[38];
  const float* hb2      = (const float*)d_in[39];
  const float* h3_w     = (const float*)d_in[40];
  const float* h3_b     = (const float*)d_in[41];
  float* out = (float*)d_out;

  // ---- workspace layout (floats), total 24,906,752 = 99.6 MB ----
  float* ws = (float*)d_ws;
  float* B  = ws;
  float* QF = B;                                       // 12,582,912 floats
  unsigned short* AThi = (unsigned short*)(B + 12582912);  // 4,194,304 shorts
  unsigned short* ATlo = AThi + 4194304;
  unsigned short* MIDhi = (unsigned short*)B;              // 16,777,216 shorts
  unsigned short* MIDlo = MIDhi + 16777216;

  unsigned short* Xhi = (unsigned short*)(ws + 16777216);  // 4,194,304 shorts
  unsigned short* Xlo = Xhi + 4194304;

  unsigned short* Wqkv_hi = (unsigned short*)(ws + 20971520); // 786,432
  unsigned short* Wqkv_lo = Wqkv_hi + 786432;
  unsigned short* Wao_hi  = Wqkv_lo + 786432;    // 262,144
  unsigned short* Wao_lo  = Wao_hi + 262144;
  unsigned short* Wf1_hi  = Wao_lo + 262144;     // 1,048,576
  unsigned short* Wf1_lo  = Wf1_hi + 1048576;
  unsigned short* Wf2_hi  = Wf1_lo + 1048576;    // 1,048,576
  unsigned short* Wf2_lo  = Wf2_hi + 1048576;    // ends at ws + 24,117,248 floats

  float* FE = ws + 24117248;         //   262,144
  float* XM = FE + 262144;           //   524,288
  float* PW = XM + 524288;           //     2,048
  float* HP = PW + 2048;             //     1,024

  // mamba aliases overlay B
  float* XZ   = B;                 // 2,097,152 (1024x2048)
  float* XC   = B + 2097152;       // 1,048,576
  float* DT   = B + 3145728;       // 1,048,576
  float* XDBL = B + 4194304;       //    65,536
  float* Y    = B + 4259840;       // 1,048,576
  float* TMP  = B + 5308416;       //   524,288
  float* HEND = B + 5832704;       //   524,288
  float* PPR  = B + 6356992;       //   524,288
  float* CIN  = B + 6881280;       //   524,288

  // ---- weight prep: 4 batched launches (z = layer) ----
  wsplit_kernel<<<dim3(24,8,4),256,0,stream>>>(qkv_w, Wqkv_hi, Wqkv_lo, 256, 768, 196608, 196608);
  wsplit_kernel<<<dim3(8,8,4),256,0,stream>>>(ao_w, Wao_hi, Wao_lo, 256, 256, 65536, 65536);
  wsplit_kernel<<<dim3(32,8,4),256,0,stream>>>(ffn_w1, Wf1_hi, Wf1_lo, 256, 1024, 262144, 262144);
  wsplit_kernel<<<dim3(8,32,4),256,0,stream>>>(ffn_w2, Wf2_hi, Wf2_lo, 1024, 256, 262144, 262144);

  // ---- encoder: 4 chunks of 256 sequences (16384 rows) ----
  for (int ch = 0; ch < 4; ch++) {
    int n0 = ch * 256;
    const float* fch = frames + (size_t)n0 * 64 * 32;
    gemm128_kernel<ACT_NONE,1,1><<<dim3(2,128),256,0,stream>>>(
        fch, in_w, in_b, pos_emb, QF, Xhi, Xlo, 32, 32, 256, 256);
    for (int l = 0; l < 4; l++) {
      gemm_bf16x2_kernel<ACT_NONE,0><<<dim3(6,128),256,0,stream>>>(
          Xhi, Xlo, Wqkv_hi + l*196608, Wqkv_lo + l*196608, qkv_b + l*768,
          QF, nullptr, nullptr, 256, 256, 256, 768);
      attn_fused_kernel<<<2048,64,0,stream>>>(QF, fmask, AThi, ATlo, n0);
      gemm_ln_kernel<<<512,256,0,stream>>>(
          AThi, ATlo, Wao_hi + l*65536, Wao_lo + l*65536, ao_b + l*256,
          ln1_g + l*256, ln1_b + l*256, Xhi, Xlo, 256, 256, 256);
      gemm_bf16x2_kernel<ACT_GELU,2><<<dim3(8,128),256,0,stream>>>(
          Xhi, Xlo, Wf1_hi + l*262144, Wf1_lo + l*262144, ffn_b1 + l*1024,
          nullptr, MIDhi, MIDlo, 256, 256, 256, 1024);
      gemm_ln_kernel<<<512,256,0,stream>>>(
          MIDhi, MIDlo, Wf2_hi + l*262144, Wf2_lo + l*262144, ffn_b2 + l*256,
          ln2_g + l*256, ln2_b + l*256, Xhi, Xlo, 1024, 1024, 1024);
    }
    mean_kernel<<<256,256,0,stream>>>(Xhi, Xlo, fmask, FE, n0);
  }

  gemm64_kernel<ACT_NONE><<<dim3(8,16),256,0,stream>>>(FE, proj_w, proj_b, XM, 256, 256, 512, 512);

  for (int l = 0; l < 8; l++) {
    gemm64_kernel<ACT_NONE><<<dim3(32,16),256,0,stream>>>(
        XM, m_in_w + (size_t)l*512*2048, nullptr, XZ, 512, 512, 2048, 2048);
    conv_kernel<<<4096,256,0,stream>>>(XZ, m_conv_w + l*1024*4, m_conv_b + l*1024, XC);
    gemm64_kernel<ACT_NONE><<<dim3(1,16),256,0,stream>>>(
        XC, m_xproj_w + (size_t)l*1024*64, nullptr, XDBL, 1024, 1024, 64, 64);
    gemm64_kernel<ACT_SOFTPLUS><<<dim3(16,16),256,0,stream>>>(
        XDBL, m_dt_w + (size_t)l*32*1024, m_dt_b + l*1024, DT, 32, 64, 1024, 1024);
    scan1_kernel<<<128,256,0,stream>>>(DT, XC, XDBL, m_Alog + l*16384, HEND, PPR);
    scan2_kernel<<<64,256,0,stream>>>(HEND, PPR, CIN);
    scan3_kernel<<<128,256,0,stream>>>(DT, XC, XDBL, m_Alog + l*16384, CIN, m_D + l*1024, XZ, Y);
    gemm64_kernel<ACT_NONE><<<dim3(8,16),256,0,stream>>>(
        Y, m_out_w + (size_t)l*1024*512, nullptr, TMP, 1024, 1024, 512, 512);
    ln_res_kernel<<<256,256,0,stream>>>(TMP, XM, m_ln_g + l*512, m_ln_b + l*512, XM, 512);
  }

  pool1_kernel<<<1,1024,0,stream>>>(XM, pool_w, pool_b, PW);
  pool2_kernel<<<2,256,0,stream>>>(XM, PW, HP);
  head_kernel<<<1,128,0,stream>>>(HP, h1_w, h1_b, hg1, hb1, h2_w, h2_b, hg2, hb2, h3_w, h3_b, out);
  copyx_kernel<<<2048,256,0,stream>>>(XM, out);
}

// Round 9
// 5405.286 us; speedup vs baseline: 1.3678x; 1.3678x over previous
//
#include <hip/hip_runtime.h>
#include <math.h>

#define ACT_NONE 0
#define ACT_GELU 1
#define ACT_SOFTPLUS 2

template<int ACT>
__device__ __forceinline__ float act_apply(float x){
  if (ACT == ACT_GELU)     return 0.5f * x * (1.0f + erff(x * 0.70710678118654752f));
  if (ACT == ACT_SOFTPLUS) return fmaxf(x, 0.0f) + log1pf(expf(-fabsf(x)));
  return x;
}

// ---------------- bf16 split helpers ----------------
__device__ __forceinline__ unsigned short f2bf(float x){
  unsigned u = __float_as_uint(x);
  u = u + 0x7FFFu + ((u >> 16) & 1u);
  return (unsigned short)(u >> 16);
}
__device__ __forceinline__ float bf2f(unsigned short b){
  return __uint_as_float(((unsigned)b) << 16);
}
__device__ __forceinline__ void bfsplit(float x, unsigned short &hi, unsigned short &lo){
  hi = f2bf(x);
  lo = f2bf(x - bf2f(hi));
}

typedef __attribute__((ext_vector_type(8))) short v8s;
typedef __attribute__((ext_vector_type(4))) float v4f;

// ---------------- bf16x2 MFMA GEMM: 128x128 tile, 256 thr (4 waves) ------------
// A [M][K] bf16 hi/lo; B TRANSPOSED [N][K] bf16 hi/lo.
// OUT: 0 = fp32 store (+bias), 2 = bf16-split store.
// R7: software-pipelined staging (kept — it helped; 8 uint4 prefetch, no spill).
template<int ACT, int OUT>
__global__ __launch_bounds__(256) void gemm_bf16x2_kernel(
    const unsigned short* __restrict__ Ahi, const unsigned short* __restrict__ Alo,
    const unsigned short* __restrict__ Bhi, const unsigned short* __restrict__ Blo,
    const float* __restrict__ bias, float* __restrict__ C,
    unsigned short* __restrict__ Chi, unsigned short* __restrict__ Clo,
    int K, int lda, int ldb, int ldc)
{
  __shared__ unsigned short As[2][128][40];
  __shared__ unsigned short Bs[2][128][40];
  const int tid = threadIdx.x;
  const int m0 = blockIdx.y * 128;
  const int n0 = blockIdx.x * 128;
  const int w = tid >> 6, lane = tid & 63;
  const int wm = (w & 1) * 64, wn = (w >> 1) * 64;
  const int fm = lane & 15, fq = lane >> 4;
  const int r = tid >> 1, h = tid & 1;

  const unsigned short* pAh = Ahi + (size_t)(m0 + r) * lda + h * 16;
  const unsigned short* pAl = Alo + (size_t)(m0 + r) * lda + h * 16;
  const unsigned short* pBh = Bhi + (size_t)(n0 + r) * ldb + h * 16;
  const unsigned short* pBl = Blo + (size_t)(n0 + r) * ldb + h * 16;

  v4f acc[4][4];
#pragma unroll
  for (int i = 0; i < 4; i++)
#pragma unroll
    for (int j = 0; j < 4; j++) acc[i][j] = (v4f){0.f, 0.f, 0.f, 0.f};

  uint4 ah0 = *(const uint4*)(pAh),     ah1 = *(const uint4*)(pAh + 8);
  uint4 al0 = *(const uint4*)(pAl),     al1 = *(const uint4*)(pAl + 8);
  uint4 bh0 = *(const uint4*)(pBh),     bh1 = *(const uint4*)(pBh + 8);
  uint4 bl0 = *(const uint4*)(pBl),     bl1 = *(const uint4*)(pBl + 8);

  for (int k0 = 0; k0 < K; k0 += 32) {
    __syncthreads();
    *(uint4*)&As[0][r][h * 16]     = ah0;
    *(uint4*)&As[0][r][h * 16 + 8] = ah1;
    *(uint4*)&As[1][r][h * 16]     = al0;
    *(uint4*)&As[1][r][h * 16 + 8] = al1;
    *(uint4*)&Bs[0][r][h * 16]     = bh0;
    *(uint4*)&Bs[0][r][h * 16 + 8] = bh1;
    *(uint4*)&Bs[1][r][h * 16]     = bl0;
    *(uint4*)&Bs[1][r][h * 16 + 8] = bl1;
    __syncthreads();

    if (k0 + 32 < K) {
      int kn = k0 + 32;
      ah0 = *(const uint4*)(pAh + kn); ah1 = *(const uint4*)(pAh + kn + 8);
      al0 = *(const uint4*)(pAl + kn); al1 = *(const uint4*)(pAl + kn + 8);
      bh0 = *(const uint4*)(pBh + kn); bh1 = *(const uint4*)(pBh + kn + 8);
      bl0 = *(const uint4*)(pBl + kn); bl1 = *(const uint4*)(pBl + kn + 8);
    }

    v8s ah[4], al[4];
#pragma unroll
    for (int i = 0; i < 4; i++) {
      ah[i] = *(const v8s*)&As[0][wm + i * 16 + fm][fq * 8];
      al[i] = *(const v8s*)&As[1][wm + i * 16 + fm][fq * 8];
    }
#pragma unroll
    for (int j = 0; j < 4; j++) {
      v8s bh = *(const v8s*)&Bs[0][wn + j * 16 + fm][fq * 8];
      v8s bl = *(const v8s*)&Bs[1][wn + j * 16 + fm][fq * 8];
#pragma unroll
      for (int i = 0; i < 4; i++) {
        acc[i][j] = __builtin_amdgcn_mfma_f32_16x16x32_bf16(ah[i], bh, acc[i][j], 0, 0, 0);
        acc[i][j] = __builtin_amdgcn_mfma_f32_16x16x32_bf16(ah[i], bl, acc[i][j], 0, 0, 0);
        acc[i][j] = __builtin_amdgcn_mfma_f32_16x16x32_bf16(al[i], bh, acc[i][j], 0, 0, 0);
      }
    }
  }

#pragma unroll
  for (int i = 0; i < 4; i++)
#pragma unroll
    for (int j = 0; j < 4; j++) {
      int col = n0 + wn + j * 16 + fm;
      float bv = bias ? bias[col] : 0.0f;
#pragma unroll
      for (int reg = 0; reg < 4; reg++) {
        int row = m0 + wm + i * 16 + fq * 4 + reg;
        float v = acc[i][j][reg] + bv;
        v = act_apply<ACT>(v);
        size_t idx = (size_t)row * ldc + col;
        if (OUT == 0) C[idx] = v;
        else { unsigned short hi, lo; bfsplit(v, hi, lo); Chi[idx] = hi; Clo[idx] = lo; }
      }
    }
}

// ------- fused GEMM(bf16x2) + residual + LayerNorm + split write ---------------
// tile 32 rows x 256 cols, 256 thr. X <- LN(X + A@B + bias)*g + beta (in-place).
// R9: REVERTED to R7's non-pipelined staging — R8's register prefetch (9 uint4
// live across MFMA) spilled to scratch (WRITE_SIZE 176 MB, 166 µs/dispatch).
// Load->store-immediately keeps nothing live across barriers.
__global__ __launch_bounds__(256) void gemm_ln_kernel(
    const unsigned short* __restrict__ Ahi, const unsigned short* __restrict__ Alo,
    const unsigned short* __restrict__ Bhi, const unsigned short* __restrict__ Blo,
    const float* __restrict__ bias,
    const float* __restrict__ g, const float* __restrict__ beta,
    unsigned short* __restrict__ Xhi, unsigned short* __restrict__ Xlo,
    int K, int lda, int ldb)
{
  __shared__ unsigned short As[2][32][40];
  __shared__ unsigned short Bs[2][256][40];
  __shared__ float rs[32][5];
  __shared__ float ms[32][2];
  const int tid = threadIdx.x;
  const int m0 = blockIdx.x * 32;
  const int w = tid >> 6, lane = tid & 63;
  const int fm = lane & 15, fq = lane >> 4;
  const int a_sel = tid >> 7;
  const int a_row = (tid >> 2) & 31;
  const int a_c   = tid & 3;
  const int b_row = tid >> 2;
  const int b_c   = tid & 3;

  v4f acc[2][4];
#pragma unroll
  for (int i = 0; i < 2; i++)
#pragma unroll
    for (int j = 0; j < 4; j++) acc[i][j] = (v4f){0.f, 0.f, 0.f, 0.f};

  for (int k0 = 0; k0 < K; k0 += 32) {
    __syncthreads();   // previous compute done before LDS overwrite
    {
      const unsigned short* asrc = (a_sel ? Alo : Ahi) + (size_t)(m0 + a_row) * lda + k0 + a_c * 8;
      *(uint4*)&As[a_sel][a_row][a_c * 8] = *(const uint4*)asrc;
    }
#pragma unroll
    for (int p = 0; p < 4; p++) {
      int row = p * 64 + b_row;
      *(uint4*)&Bs[0][row][b_c * 8] = *(const uint4*)(Bhi + (size_t)row * ldb + k0 + b_c * 8);
      *(uint4*)&Bs[1][row][b_c * 8] = *(const uint4*)(Blo + (size_t)row * ldb + k0 + b_c * 8);
    }
    __syncthreads();

    v8s ah[2], al[2];
#pragma unroll
    for (int i = 0; i < 2; i++) {
      ah[i] = *(const v8s*)&As[0][i * 16 + fm][fq * 8];
      al[i] = *(const v8s*)&As[1][i * 16 + fm][fq * 8];
    }
#pragma unroll
    for (int j = 0; j < 4; j++) {
      v8s bhf = *(const v8s*)&Bs[0][w * 64 + j * 16 + fm][fq * 8];
      v8s blf = *(const v8s*)&Bs[1][w * 64 + j * 16 + fm][fq * 8];
#pragma unroll
      for (int i = 0; i < 2; i++) {
        acc[i][j] = __builtin_amdgcn_mfma_f32_16x16x32_bf16(ah[i], bhf, acc[i][j], 0, 0, 0);
        acc[i][j] = __builtin_amdgcn_mfma_f32_16x16x32_bf16(ah[i], blf, acc[i][j], 0, 0, 0);
        acc[i][j] = __builtin_amdgcn_mfma_f32_16x16x32_bf16(al[i], bhf, acc[i][j], 0, 0, 0);
      }
    }
  }

  // acc <- x_old + delta + bias
#pragma unroll
  for (int i = 0; i < 2; i++)
#pragma unroll
    for (int j = 0; j < 4; j++) {
      int cl = w * 64 + j * 16 + fm;
      float bv = bias[cl];
#pragma unroll
      for (int reg = 0; reg < 4; reg++) {
        int rl = i * 16 + fq * 4 + reg;
        size_t idx = (size_t)(m0 + rl) * 256 + cl;
        acc[i][j][reg] += bv + bf2f(Xhi[idx]) + bf2f(Xlo[idx]);
      }
    }
  // mean
#pragma unroll
  for (int i = 0; i < 2; i++)
#pragma unroll
    for (int reg = 0; reg < 4; reg++) {
      float s = acc[i][0][reg] + acc[i][1][reg] + acc[i][2][reg] + acc[i][3][reg];
      s += __shfl_xor(s, 1); s += __shfl_xor(s, 2);
      s += __shfl_xor(s, 4); s += __shfl_xor(s, 8);
      if (fm == 0) rs[i * 16 + fq * 4 + reg][w] = s;
    }
  __syncthreads();
  if (tid < 32) ms[tid][0] = (rs[tid][0] + rs[tid][1] + rs[tid][2] + rs[tid][3]) * (1.0f / 256.0f);
  __syncthreads();
  // var
#pragma unroll
  for (int i = 0; i < 2; i++)
#pragma unroll
    for (int reg = 0; reg < 4; reg++) {
      int rl = i * 16 + fq * 4 + reg;
      float mean = ms[rl][0];
      float s = 0.0f;
#pragma unroll
      for (int j = 0; j < 4; j++) { float d = acc[i][j][reg] - mean; s += d * d; }
      s += __shfl_xor(s, 1); s += __shfl_xor(s, 2);
      s += __shfl_xor(s, 4); s += __shfl_xor(s, 8);
      if (fm == 0) rs[rl][w] = s;
    }
  __syncthreads();
  if (tid < 32) {
    float var = (rs[tid][0] + rs[tid][1] + rs[tid][2] + rs[tid][3]) * (1.0f / 256.0f);
    ms[tid][1] = rsqrtf(var + 1e-5f);
  }
  __syncthreads();
#pragma unroll
  for (int i = 0; i < 2; i++)
#pragma unroll
    for (int j = 0; j < 4; j++) {
      int cl = w * 64 + j * 16 + fm;
      float gv = g[cl], bv = beta[cl];
#pragma unroll
      for (int reg = 0; reg < 4; reg++) {
        int rl = i * 16 + fq * 4 + reg;
        float t = (acc[i][j][reg] - ms[rl][0]) * ms[rl][1] * gv + bv;
        size_t idx = (size_t)(m0 + rl) * 256 + cl;
        unsigned short hi, lo; bfsplit(t, hi, lo);
        Xhi[idx] = hi; Xlo[idx] = lo;
      }
    }
}

// -------- weight transpose + split (batched over layers via blockIdx.z) --------
__global__ __launch_bounds__(256) void wsplit_kernel(
    const float* __restrict__ W, unsigned short* __restrict__ Whi,
    unsigned short* __restrict__ Wlo, int K, int N, size_t wstride, size_t ostride)
{
  __shared__ float tile[32][33];
  const float* Wl = W + blockIdx.z * wstride;
  unsigned short* Whl = Whi + blockIdx.z * ostride;
  unsigned short* Wll = Wlo + blockIdx.z * ostride;
  int k0 = blockIdx.y * 32, n0 = blockIdx.x * 32;
  int t = threadIdx.x;
  int tn = t & 31, tk8 = t >> 5;
#pragma unroll
  for (int i = 0; i < 4; i++) {
    int k = tk8 + i * 8;
    tile[k][tn] = Wl[(size_t)(k0 + k) * N + n0 + tn];
  }
  __syncthreads();
  int tk = t & 31, tn8 = t >> 5;
#pragma unroll
  for (int i = 0; i < 4; i++) {
    int n = tn8 + i * 8;
    float v = tile[tk][n];
    unsigned short hi, lo; bfsplit(v, hi, lo);
    size_t idx = (size_t)(n0 + n) * K + k0 + tk;
    Whl[idx] = hi; Wll[idx] = lo;
  }
}

// ------------- fp32 GEMM 128x128 (embed only), POS + split write ---------------
template<int ACT, int POS, int SPLIT>
__global__ __launch_bounds__(256) void gemm128_kernel(
    const float* __restrict__ A, const float* __restrict__ W,
    const float* __restrict__ bias, const float* __restrict__ pos,
    float* __restrict__ C, unsigned short* __restrict__ Chi, unsigned short* __restrict__ Clo,
    int K, int lda, int ldw, int ldc)
{
  __shared__ float As[16][128];
  __shared__ float Ws[16][128];
  const int tid = threadIdx.x;
  const int m0 = blockIdx.y * 128;
  const int n0 = blockIdx.x * 128;
  const int tx = tid & 15, ty = tid >> 4;
  const int ar = tid >> 2, ak = (tid & 3) * 4;
  const int wk = tid >> 5, wn = (tid & 31) * 4;

  float acc[8][8];
#pragma unroll
  for (int i = 0; i < 8; i++)
#pragma unroll
    for (int j = 0; j < 8; j++) acc[i][j] = 0.0f;

  for (int k0 = 0; k0 < K; k0 += 16) {
    float4 a0 = *(const float4*)(A + (size_t)(m0 + ar)      * lda + k0 + ak);
    float4 a1 = *(const float4*)(A + (size_t)(m0 + ar + 64) * lda + k0 + ak);
    float4 w0 = *(const float4*)(W + (size_t)(k0 + wk)     * ldw + n0 + wn);
    float4 w1 = *(const float4*)(W + (size_t)(k0 + wk + 8) * ldw + n0 + wn);
    __syncthreads();
    As[ak + 0][ar] = a0.x; As[ak + 1][ar] = a0.y; As[ak + 2][ar] = a0.z; As[ak + 3][ar] = a0.w;
    As[ak + 0][ar + 64] = a1.x; As[ak + 1][ar + 64] = a1.y; As[ak + 2][ar + 64] = a1.z; As[ak + 3][ar + 64] = a1.w;
    *(float4*)&Ws[wk][wn] = w0;
    *(float4*)&Ws[wk + 8][wn] = w1;
    __syncthreads();
#pragma unroll
    for (int k = 0; k < 16; k++) {
      float4 xa = *(float4*)&As[k][ty * 8];
      float4 xb = *(float4*)&As[k][ty * 8 + 4];
      float4 y0 = *(float4*)&Ws[k][tx * 8];
      float4 y1 = *(float4*)&Ws[k][tx * 8 + 4];
      float a8[8] = {xa.x, xa.y, xa.z, xa.w, xb.x, xb.y, xb.z, xb.w};
      float b8[8] = {y0.x, y0.y, y0.z, y0.w, y1.x, y1.y, y1.z, y1.w};
#pragma unroll
      for (int i = 0; i < 8; i++)
#pragma unroll
        for (int j = 0; j < 8; j++) acc[i][j] = fmaf(a8[i], b8[j], acc[i][j]);
    }
  }
#pragma unroll
  for (int i = 0; i < 8; i++) {
    int row = m0 + ty * 8 + i;
    float* cp = C + (size_t)row * ldc + n0 + tx * 8;
    float v[8];
#pragma unroll
    for (int j = 0; j < 8; j++) {
      float t = acc[i][j];
      int col = n0 + tx * 8 + j;
      if (bias) t += bias[col];
      if (POS)  t += pos[(row & 63) * 256 + col];
      t = act_apply<ACT>(t);
      v[j] = t;
      if (SPLIT) {
        unsigned short hi, lo; bfsplit(t, hi, lo);
        size_t idx = (size_t)row * ldc + col;
        Chi[idx] = hi; Clo[idx] = lo;
      }
    }
    *(float4*)cp       = make_float4(v[0], v[1], v[2], v[3]);
    *(float4*)(cp + 4) = make_float4(v[4], v[5], v[6], v[7]);
  }
}

// ---------------- GEMM 64x64 tile fp32 (mamba), pipelined ----------------
template<int ACT>
__global__ __launch_bounds__(256) void gemm64_kernel(
    const float* __restrict__ A, const float* __restrict__ W,
    const float* __restrict__ bias, float* __restrict__ C,
    int K, int lda, int ldw, int ldc)
{
  __shared__ float As[16][64];
  __shared__ float Ws[16][64];
  const int tid = threadIdx.x;
  const int m0 = blockIdx.y * 64;
  const int n0 = blockIdx.x * 64;
  const int tx = tid & 15, ty = tid >> 4;
  const int ar = tid >> 2, ak = (tid & 3) * 4;
  const int wk = tid >> 4, wn = (tid & 15) * 4;

  float acc[4][4];
#pragma unroll
  for (int i = 0; i < 4; i++)
#pragma unroll
    for (int j = 0; j < 4; j++) acc[i][j] = 0.0f;

  float4 a0 = *(const float4*)(A + (size_t)(m0 + ar) * lda + ak);
  float4 w0 = *(const float4*)(W + (size_t)wk * ldw + n0 + wn);

  for (int k0 = 0; k0 < K; k0 += 16) {
    __syncthreads();
    As[ak + 0][ar] = a0.x; As[ak + 1][ar] = a0.y; As[ak + 2][ar] = a0.z; As[ak + 3][ar] = a0.w;
    *(float4*)&Ws[wk][wn] = w0;
    __syncthreads();
    if (k0 + 16 < K) {
      a0 = *(const float4*)(A + (size_t)(m0 + ar) * lda + k0 + 16 + ak);
      w0 = *(const float4*)(W + (size_t)(k0 + 16 + wk) * ldw + n0 + wn);
    }
#pragma unroll
    for (int k = 0; k < 16; k++) {
      float4 xa = *(float4*)&As[k][ty * 4];
      float4 yb = *(float4*)&Ws[k][tx * 4];
      float a4[4] = {xa.x, xa.y, xa.z, xa.w};
      float b4[4] = {yb.x, yb.y, yb.z, yb.w};
#pragma unroll
      for (int i = 0; i < 4; i++)
#pragma unroll
        for (int j = 0; j < 4; j++) acc[i][j] = fmaf(a4[i], b4[j], acc[i][j]);
    }
  }
#pragma unroll
  for (int i = 0; i < 4; i++) {
    float* cp = C + (size_t)(m0 + ty * 4 + i) * ldc + n0 + tx * 4;
    float v[4];
#pragma unroll
    for (int j = 0; j < 4; j++) {
      float t = acc[i][j];
      if (bias) t += bias[n0 + tx * 4 + j];
      v[j] = act_apply<ACT>(t);
    }
    *(float4*)cp = make_float4(v[0], v[1], v[2], v[3]);
  }
}

// ---------------- fused attention; writes bf16-split AT ----------------
__global__ __launch_bounds__(64) void attn_fused_kernel(
    const float* __restrict__ QKVc, const float* __restrict__ mask,
    unsigned short* __restrict__ AThi, unsigned short* __restrict__ ATlo, int n0)
{
  int bid = blockIdx.x;
  int nl = bid >> 3;
  int h = bid & 7;
  int n = n0 + nl;
  int tid = threadIdx.x;
  int tx = tid & 7, ty = tid >> 3;
  __shared__ float Qt[32][68];
  __shared__ float Kt[32][68];
  __shared__ float Vs[64][36];
  __shared__ float Pt[64][68];
  __shared__ float bs[64];
  const float* base = QKVc + (size_t)nl * (64 * 768);
#pragma unroll
  for (int i = 0; i < 32; i++) {
    int idx = tid + i * 64;
    int bar = idx >> 5, c = idx & 31;
    Qt[c][bar] = base[bar * 768 + h * 32 + c];
    Kt[c][bar] = base[bar * 768 + 256 + h * 32 + c];
    Vs[bar][c] = base[bar * 768 + 512 + h * 32 + c];
  }
  bs[tid] = (1.0f - mask[n * 64 + tid]) * -1e9f;
  __syncthreads();
  float acc[8][8] = {};
  for (int c = 0; c < 32; c++) {
    float4 ax = *(float4*)&Qt[c][ty * 8];
    float4 ay = *(float4*)&Qt[c][ty * 8 + 4];
    float4 bx = *(float4*)&Kt[c][tx * 8];
    float4 by = *(float4*)&Kt[c][tx * 8 + 4];
    float a8[8] = {ax.x, ax.y, ax.z, ax.w, ay.x, ay.y, ay.z, ay.w};
    float b8[8] = {bx.x, bx.y, bx.z, bx.w, by.x, by.y, by.z, by.w};
#pragma unroll
    for (int i = 0; i < 8; i++)
#pragma unroll
      for (int j = 0; j < 8; j++) acc[i][j] = fmaf(a8[i], b8[j], acc[i][j]);
  }
  const float scale = 0.17677669529663687f;
#pragma unroll
  for (int i = 0; i < 8; i++) {
    float s[8];
    float mx = -3.0e38f;
#pragma unroll
    for (int j = 0; j < 8; j++) { s[j] = acc[i][j] * scale + bs[tx * 8 + j]; mx = fmaxf(mx, s[j]); }
#pragma unroll
    for (int off = 1; off < 8; off <<= 1) mx = fmaxf(mx, __shfl_xor(mx, off));
    float sum = 0.0f;
#pragma unroll
    for (int j = 0; j < 8; j++) { s[j] = expf(s[j] - mx); sum += s[j]; }
#pragma unroll
    for (int off = 1; off < 8; off <<= 1) sum += __shfl_xor(sum, off);
    float inv = 1.0f / sum;
#pragma unroll
    for (int j = 0; j < 8; j++) Pt[tx * 8 + j][ty * 8 + i] = s[j] * inv;
  }
  __syncthreads();
  float o[8][4] = {};
  for (int j = 0; j < 64; j++) {
    float4 px = *(float4*)&Pt[j][ty * 8];
    float4 py = *(float4*)&Pt[j][ty * 8 + 4];
    float4 v  = *(float4*)&Vs[j][tx * 4];
    float p8[8] = {px.x, px.y, px.z, px.w, py.x, py.y, py.z, py.w};
#pragma unroll
    for (int i = 0; i < 8; i++) {
      o[i][0] = fmaf(p8[i], v.x, o[i][0]);
      o[i][1] = fmaf(p8[i], v.y, o[i][1]);
      o[i][2] = fmaf(p8[i], v.z, o[i][2]);
      o[i][3] = fmaf(p8[i], v.w, o[i][3]);
    }
  }
#pragma unroll
  for (int i = 0; i < 8; i++) {
    size_t base_o = (size_t)(nl * 64 + ty * 8 + i) * 256 + h * 32 + tx * 4;
#pragma unroll
    for (int c = 0; c < 4; c++) {
      unsigned short hi, lo; bfsplit(o[i][c], hi, lo);
      AThi[base_o + c] = hi; ATlo[base_o + c] = lo;
    }
  }
}

// ---------------- LayerNorm wave-per-row (mamba): o = LN(a)*g+beta + b ----------
__global__ __launch_bounds__(256) void ln_res_kernel(
    const float* __restrict__ a, const float* __restrict__ b,
    const float* __restrict__ g, const float* __restrict__ beta,
    float* __restrict__ o, int Wd)
{
  int wave = threadIdx.x >> 6;
  int lane = threadIdx.x & 63;
  int row = blockIdx.x * 4 + wave;
  int P = Wd >> 6;
  const float* ar = a + (size_t)row * Wd;
  const float* br = b + (size_t)row * Wd;
  float v[8];
  float s = 0.0f;
  for (int i = 0; i < P; i++) { float x = ar[lane + i * 64]; v[i] = x; s += x; }
#pragma unroll
  for (int off = 32; off; off >>= 1) s += __shfl_xor(s, off);
  float mean = s / Wd;
  float vs = 0.0f;
  for (int i = 0; i < P; i++) { float d = v[i] - mean; vs += d * d; }
#pragma unroll
  for (int off = 32; off; off >>= 1) vs += __shfl_xor(vs, off);
  float rstd = rsqrtf(vs / Wd + 1e-5f);
  for (int i = 0; i < P; i++) {
    int col = lane + i * 64;
    o[(size_t)row * Wd + col] = (v[i] - mean) * rstd * g[col] + beta[col] + br[col];
  }
}

// ------------- masked mean over bars (reads hi/lo X) ---------------------------
__global__ __launch_bounds__(256) void mean_kernel(
    const unsigned short* __restrict__ Xhi, const unsigned short* __restrict__ Xlo,
    const float* __restrict__ mask, float* __restrict__ FE, int n0)
{
  int n = blockIdx.x;
  int c = threadIdx.x;
  float s = 0.0f, ms = 0.0f;
  for (int bar = 0; bar < 64; bar++) {
    float mk = mask[(n0 + n) * 64 + bar];
    size_t idx = (size_t)(n * 64 + bar) * 256 + c;
    s = fmaf(bf2f(Xhi[idx]) + bf2f(Xlo[idx]), mk, s);
    ms += mk;
  }
  FE[(n0 + n) * 256 + c] = s / fmaxf(ms, 1.0f);
}

// ---------------- mamba conv (4-tap causal) + silu ----------------
__global__ __launch_bounds__(256) void conv_kernel(
    const float* __restrict__ XZ, const float* __restrict__ w,
    const float* __restrict__ b, float* __restrict__ XC)
{
  int idx = blockIdx.x * 256 + threadIdx.x;
  int t = idx >> 10, c = idx & 1023;
  float acc = b[c];
  const float* wc = w + c * 4;
#pragma unroll
  for (int k = 0; k < 4; k++) {
    int tt = t + k - 3;
    if (tt >= 0) acc = fmaf(XZ[(size_t)tt * 2048 + c], wc[k], acc);
  }
  XC[idx] = acc / (1.0f + expf(-acc));
}

// ---------------- chunked scan (32 chunks x 32 steps) ----------------
#define NCH 32
#define CLEN 32

__global__ __launch_bounds__(256) void scan1_kernel(
    const float* __restrict__ DT, const float* __restrict__ XC,
    const float* __restrict__ XDBL, const float* __restrict__ Alog,
    float* __restrict__ HEND, float* __restrict__ PPR)
{
  int j = blockIdx.x >> 2;
  int c = (blockIdx.x & 3) * 256 + threadIdx.x;
  int t0 = j * CLEN;
  __shared__ float Bs[CLEN][16];
  for (int i = threadIdx.x; i < CLEN * 16; i += 256) {
    int r = i >> 4, s = i & 15;
    Bs[r][s] = XDBL[(t0 + r) * 64 + 32 + s];
  }
  float A[16], h[16], Pp[16];
#pragma unroll
  for (int s = 0; s < 16; s++) {
    A[s] = -expf(Alog[c * 16 + s]);
    h[s] = 0.0f; Pp[s] = 1.0f;
  }
  __syncthreads();
  for (int tt = 0; tt < CLEN; tt++) {
    int t = t0 + tt;
    float dtv = DT[(size_t)t * 1024 + c];
    float u = dtv * XC[(size_t)t * 1024 + c];
#pragma unroll
    for (int s = 0; s < 16; s++) {
      float e = expf(dtv * A[s]);
      h[s] = fmaf(h[s], e, u * Bs[tt][s]);
      Pp[s] *= e;
    }
  }
#pragma unroll
  for (int s = 0; s < 16; s++) {
    HEND[(size_t)(j * 1024 + c) * 16 + s] = h[s];
    PPR [(size_t)(j * 1024 + c) * 16 + s] = Pp[s];
  }
}

__global__ __launch_bounds__(256) void scan2_kernel(
    const float* __restrict__ HEND, const float* __restrict__ PPR, float* __restrict__ CIN)
{
  int id = blockIdx.x * 256 + threadIdx.x;
  float carry = 0.0f;
  for (int j = 0; j < NCH; j++) {
    CIN[j * 16384 + id] = carry;
    carry = fmaf(PPR[j * 16384 + id], carry, HEND[j * 16384 + id]);
  }
}

__global__ __launch_bounds__(256) void scan3_kernel(
    const float* __restrict__ DT, const float* __restrict__ XC,
    const float* __restrict__ XDBL, const float* __restrict__ Alog,
    const float* __restrict__ CIN, const float* __restrict__ mD,
    const float* __restrict__ XZ, float* __restrict__ Y)
{
  int j = blockIdx.x >> 2;
  int c = (blockIdx.x & 3) * 256 + threadIdx.x;
  int t0 = j * CLEN;
  __shared__ float Bs[CLEN][16], Cs[CLEN][16];
  for (int i = threadIdx.x; i < CLEN * 16; i += 256) {
    int r = i >> 4, s = i & 15;
    Bs[r][s] = XDBL[(t0 + r) * 64 + 32 + s];
    Cs[r][s] = XDBL[(t0 + r) * 64 + 48 + s];
  }
  float A[16], h[16];
#pragma unroll
  for (int s = 0; s < 16; s++) {
    A[s] = -expf(Alog[c * 16 + s]);
    h[s] = CIN[(size_t)(j * 1024 + c) * 16 + s];
  }
  float dval = mD[c];
  __syncthreads();
  for (int tt = 0; tt < CLEN; tt++) {
    int t = t0 + tt;
    float dtv = DT[(size_t)t * 1024 + c];
    float xcv = XC[(size_t)t * 1024 + c];
    float u = dtv * xcv;
    float y = 0.0f;
#pragma unroll
    for (int s = 0; s < 16; s++) {
      float e = expf(dtv * A[s]);
      h[s] = fmaf(h[s], e, u * Bs[tt][s]);
      y = fmaf(h[s], Cs[tt][s], y);
    }
    float z = XZ[(size_t)t * 2048 + 1024 + c];
    float sz = z / (1.0f + expf(-z));
    Y[(size_t)t * 1024 + c] = (y + dval * xcv) * sz;
  }
}

// ---------------- pooling + head ----------------
__global__ __launch_bounds__(1024) void pool1_kernel(
    const float* __restrict__ XM, const float* __restrict__ pw,
    const float* __restrict__ pb, float* __restrict__ PW)
{
  int t = threadIdx.x;
  float s = pb[0];
  for (int i = 0; i < 512; i++) s = fmaf(XM[(size_t)t * 512 + i], pw[i], s);
  __shared__ float red[1024];
  red[t] = s;
  __syncthreads();
  for (int off = 512; off > 0; off >>= 1) {
    if (t < off) red[t] = fmaxf(red[t], red[t + off]);
    __syncthreads();
  }
  float mx = red[0];
  __syncthreads();
  float e = expf(s - mx);
  red[t] = e;
  __syncthreads();
  for (int off = 512; off > 0; off >>= 1) {
    if (t < off) red[t] = red[t] + red[t + off];
    __syncthreads();
  }
  PW[t] = e / red[0];
}

__global__ __launch_bounds__(256) void pool2_kernel(
    const float* __restrict__ XM, const float* __restrict__ PW, float* __restrict__ HP)
{
  int hcol = blockIdx.x * 256 + threadIdx.x;
  float s = 0.0f;
  for (int tn = 0; tn < 1024; tn++) s = fmaf(PW[tn], XM[(size_t)tn * 512 + hcol], s);
  HP[hcol] = s;
}

__device__ __forceinline__ float blk_reduce_sum_128(float v, float* red){
  int t = threadIdx.x;
#pragma unroll
  for (int off = 32; off; off >>= 1) v += __shfl_xor(v, off);
  __syncthreads();
  if ((t & 63) == 0) red[t >> 6] = v;
  __syncthreads();
  return red[0] + red[1];
}

__global__ __launch_bounds__(128) void head_kernel(
    const float* __restrict__ HP, const float* __restrict__ h1w, const float* __restrict__ h1b,
    const float* __restrict__ g1, const float* __restrict__ be1,
    const float* __restrict__ h2w, const float* __restrict__ h2b,
    const float* __restrict__ g2, const float* __restrict__ be2,
    const float* __restrict__ h3w, const float* __restrict__ h3b,
    float* __restrict__ out)
{
  __shared__ float t1[128];
  __shared__ float red[2];
  int i = threadIdx.x;
  float s = h1b[i];
  for (int k = 0; k < 512; k++) s = fmaf(HP[k], h1w[k * 128 + i], s);
  float mean = blk_reduce_sum_128(s, red) * (1.0f / 128.0f);
  float d = s - mean;
  float var = blk_reduce_sum_128(d * d, red) * (1.0f / 128.0f);
  float x1 = d * rsqrtf(var + 1e-5f) * g1[i] + be1[i];
  x1 = 0.5f * x1 * (1.0f + erff(x1 * 0.70710678118654752f));
  t1[i] = x1;
  __syncthreads();
  s = h2b[i];
  for (int k = 0; k < 128; k++) s = fmaf(t1[k], h2w[k * 128 + i], s);
  mean = blk_reduce_sum_128(s, red) * (1.0f / 128.0f);
  d = s - mean;
  var = blk_reduce_sum_128(d * d, red) * (1.0f / 128.0f);
  float x2 = d * rsqrtf(var + 1e-5f) * g2[i] + be2[i];
  x2 = 0.5f * x2 * (1.0f + erff(x2 * 0.70710678118654752f));
  float tot = blk_reduce_sum_128(x2 * h3w[i], red);
  if (i == 0) out[0] = tot + h3b[0];
}

__global__ __launch_bounds__(256) void copyx_kernel(const float* __restrict__ XM, float* __restrict__ out){
  int i = blockIdx.x * 256 + threadIdx.x;
  out[1 + i] = XM[i];
}

// ---------------- launch ----------------
extern "C" void kernel_launch(void* const* d_in, const int* in_sizes, int n_in,
                              void* d_out, int out_size, void* d_ws, size_t ws_size,
                              hipStream_t stream)
{
  const float* frames   = (const float*)d_in[0];
  const float* fmask    = (const float*)d_in[1];
  const float* in_w     = (const float*)d_in[2];
  const float* in_b     = (const float*)d_in[3];
  const float* pos_emb  = (const float*)d_in[4];
  const float* qkv_w    = (const float*)d_in[5];
  const float* qkv_b    = (const float*)d_in[6];
  const float* ao_w     = (const float*)d_in[7];
  const float* ao_b     = (const float*)d_in[8];
  const float* ln1_g    = (const float*)d_in[9];
  const float* ln1_b    = (const float*)d_in[10];
  const float* ffn_w1   = (const float*)d_in[11];
  const float* ffn_b1   = (const float*)d_in[12];
  const float* ffn_w2   = (const float*)d_in[13];
  const float* ffn_b2   = (const float*)d_in[14];
  const float* ln2_g    = (const float*)d_in[15];
  const float* ln2_b    = (const float*)d_in[16];
  const float* proj_w   = (const float*)d_in[17];
  const float* proj_b   = (const float*)d_in[18];
  const float* m_in_w   = (const float*)d_in[19];
  const float* m_conv_w = (const float*)d_in[20];
  const float* m_conv_b = (const float*)d_in[21];
  const float* m_xproj_w= (const float*)d_in[22];
  const float* m_dt_w   = (const float*)d_in[23];
  const float* m_dt_b   = (const float*)d_in[24];
  const float* m_Alog   = (const float*)d_in[25];
  const float* m_D      = (const float*)d_in[26];
  const float* m_out_w  = (const float*)d_in[27];
  const float* m_ln_g   = (const float*)d_in[28];
  const float* m_ln_b   = (const float*)d_in[29];
  const float* pool_w   = (const float*)d_in[30];
  const float* pool_b   = (const float*)d_in[31];
  const float* h1_w     = (const float*)d_in[32];
  const float* h1_b     = (const float*)d_in[33];
  const float* hg1      = (const float*)d_in[34];
  const float* hb1      = (const float*)d_in[35];
  const float* h2_w     = (const float*)d_in[36];
  const float* h2_b     = (const float*)d_in[37];
  const float* hg2      = (const float*)d_in[38];
  const float* hb2      = (const float*)d_in[39];
  const float* h3_w     = (const float*)d_in[40];
  const float* h3_b     = (const float*)d_in[41];
  float* out = (float*)d_out;

  // ---- workspace layout (floats), total 24,906,752 = 99.6 MB ----
  float* ws = (float*)d_ws;
  float* B  = ws;
  float* QF = B;                                       // 12,582,912 floats
  unsigned short* AThi = (unsigned short*)(B + 12582912);  // 4,194,304 shorts
  unsigned short* ATlo = AThi + 4194304;
  unsigned short* MIDhi = (unsigned short*)B;              // 16,777,216 shorts
  unsigned short* MIDlo = MIDhi + 16777216;

  unsigned short* Xhi = (unsigned short*)(ws + 16777216);  // 4,194,304 shorts
  unsigned short* Xlo = Xhi + 4194304;

  unsigned short* Wqkv_hi = (unsigned short*)(ws + 20971520); // 786,432
  unsigned short* Wqkv_lo = Wqkv_hi + 786432;
  unsigned short* Wao_hi  = Wqkv_lo + 786432;    // 262,144
  unsigned short* Wao_lo  = Wao_hi + 262144;
  unsigned short* Wf1_hi  = Wao_lo + 262144;     // 1,048,576
  unsigned short* Wf1_lo  = Wf1_hi + 1048576;
  unsigned short* Wf2_hi  = Wf1_lo + 1048576;    // 1,048,576
  unsigned short* Wf2_lo  = Wf2_hi + 1048576;    // ends at ws + 24,117,248 floats

  float* FE = ws + 24117248;         //   262,144
  float* XM = FE + 262144;           //   524,288
  float* PW = XM + 524288;           //     2,048
  float* HP = PW + 2048;             //     1,024

  // mamba aliases overlay B
  float* XZ   = B;                 // 2,097,152 (1024x2048)
  float* XC   = B + 2097152;       // 1,048,576
  float* DT   = B + 3145728;       // 1,048,576
  float* XDBL = B + 4194304;       //    65,536
  float* Y    = B + 4259840;       // 1,048,576
  float* TMP  = B + 5308416;       //   524,288
  float* HEND = B + 5832704;       //   524,288
  float* PPR  = B + 6356992;       //   524,288
  float* CIN  = B + 6881280;       //   524,288

  // ---- weight prep: 4 batched launches (z = layer) ----
  wsplit_kernel<<<dim3(24,8,4),256,0,stream>>>(qkv_w, Wqkv_hi, Wqkv_lo, 256, 768, 196608, 196608);
  wsplit_kernel<<<dim3(8,8,4),256,0,stream>>>(ao_w, Wao_hi, Wao_lo, 256, 256, 65536, 65536);
  wsplit_kernel<<<dim3(32,8,4),256,0,stream>>>(ffn_w1, Wf1_hi, Wf1_lo, 256, 1024, 262144, 262144);
  wsplit_kernel<<<dim3(8,32,4),256,0,stream>>>(ffn_w2, Wf2_hi, Wf2_lo, 1024, 256, 262144, 262144);

  // ---- encoder: 4 chunks of 256 sequences (16384 rows) ----
  for (int ch = 0; ch < 4; ch++) {
    int n0 = ch * 256;
    const float* fch = frames + (size_t)n0 * 64 * 32;
    gemm128_kernel<ACT_NONE,1,1><<<dim3(2,128),256,0,stream>>>(
        fch, in_w, in_b, pos_emb, QF, Xhi, Xlo, 32, 32, 256, 256);
    for (int l = 0; l < 4; l++) {
      gemm_bf16x2_kernel<ACT_NONE,0><<<dim3(6,128),256,0,stream>>>(
          Xhi, Xlo, Wqkv_hi + l*196608, Wqkv_lo + l*196608, qkv_b + l*768,
          QF, nullptr, nullptr, 256, 256, 256, 768);
      attn_fused_kernel<<<2048,64,0,stream>>>(QF, fmask, AThi, ATlo, n0);
      gemm_ln_kernel<<<512,256,0,stream>>>(
          AThi, ATlo, Wao_hi + l*65536, Wao_lo + l*65536, ao_b + l*256,
          ln1_g + l*256, ln1_b + l*256, Xhi, Xlo, 256, 256, 256);
      gemm_bf16x2_kernel<ACT_GELU,2><<<dim3(8,128),256,0,stream>>>(
          Xhi, Xlo, Wf1_hi + l*262144, Wf1_lo + l*262144, ffn_b1 + l*1024,
          nullptr, MIDhi, MIDlo, 256, 256, 256, 1024);
      gemm_ln_kernel<<<512,256,0,stream>>>(
          MIDhi, MIDlo, Wf2_hi + l*262144, Wf2_lo + l*262144, ffn_b2 + l*256,
          ln2_g + l*256, ln2_b + l*256, Xhi, Xlo, 1024, 1024, 1024);
    }
    mean_kernel<<<256,256,0,stream>>>(Xhi, Xlo, fmask, FE, n0);
  }

  gemm64_kernel<ACT_NONE><<<dim3(8,16),256,0,stream>>>(FE, proj_w, proj_b, XM, 256, 256, 512, 512);

  for (int l = 0; l < 8; l++) {
    gemm64_kernel<ACT_NONE><<<dim3(32,16),256,0,stream>>>(
        XM, m_in_w + (size_t)l*512*2048, nullptr, XZ, 512, 512, 2048, 2048);
    conv_kernel<<<4096,256,0,stream>>>(XZ, m_conv_w + l*1024*4, m_conv_b + l*1024, XC);
    gemm64_kernel<ACT_NONE><<<dim3(1,16),256,0,stream>>>(
        XC, m_xproj_w + (size_t)l*1024*64, nullptr, XDBL, 1024, 1024, 64, 64);
    gemm64_kernel<ACT_SOFTPLUS><<<dim3(16,16),256,0,stream>>>(
        XDBL, m_dt_w + (size_t)l*32*1024, m_dt_b + l*1024, DT, 32, 64, 1024, 1024);
    scan1_kernel<<<128,256,0,stream>>>(DT, XC, XDBL, m_Alog + l*16384, HEND, PPR);
    scan2_kernel<<<64,256,0,stream>>>(HEND, PPR, CIN);
    scan3_kernel<<<128,256,0,stream>>>(DT, XC, XDBL, m_Alog + l*16384, CIN, m_D + l*1024, XZ, Y);
    gemm64_kernel<ACT_NONE><<<dim3(8,16),256,0,stream>>>(
        Y, m_out_w + (size_t)l*1024*512, nullptr, TMP, 1024, 1024, 512, 512);
    ln_res_kernel<<<256,256,0,stream>>>(TMP, XM, m_ln_g + l*512, m_ln_b + l*512, XM, 512);
  }

  pool1_kernel<<<1,1024,0,stream>>>(XM, pool_w, pool_b, PW);
  pool2_kernel<<<2,256,0,stream>>>(XM, PW, HP);
  head_kernel<<<1,128,0,stream>>>(HP, h1_w, h1_b, hg1, hb1, h2_w, h2_b, hg2, hb2, h3_w, h3_b, out);
  copyx_kernel<<<2048,256,0,stream>>>(XM, out);
}

// Round 10
// 5391.579 us; speedup vs baseline: 1.3712x; 1.0025x over previous
//
#include <hip/hip_runtime.h>
#include <math.h>

#define ACT_NONE 0
#define ACT_GELU 1
#define ACT_SOFTPLUS 2

template<int ACT>
__device__ __forceinline__ float act_apply(float x){
  if (ACT == ACT_GELU)     return 0.5f * x * (1.0f + erff(x * 0.70710678118654752f));
  if (ACT == ACT_SOFTPLUS) return fmaxf(x, 0.0f) + log1pf(expf(-fabsf(x)));
  return x;
}

// ---------------- bf16 split helpers ----------------
__device__ __forceinline__ unsigned short f2bf(float x){
  unsigned u = __float_as_uint(x);
  u = u + 0x7FFFu + ((u >> 16) & 1u);
  return (unsigned short)(u >> 16);
}
__device__ __forceinline__ float bf2f(unsigned short b){
  return __uint_as_float(((unsigned)b) << 16);
}
__device__ __forceinline__ void bfsplit(float x, unsigned short &hi, unsigned short &lo){
  hi = f2bf(x);
  lo = f2bf(x - bf2f(hi));
}

typedef __attribute__((ext_vector_type(8))) short v8s;
typedef __attribute__((ext_vector_type(4))) float v4f;

// ---------------- bf16x2 MFMA GEMM: 128x128 tile, 256 thr (4 waves) ------------
// A [M][K] bf16 hi/lo; B TRANSPOSED [N][K] bf16 hi/lo.
// OUT: 0 = fp32 store (+bias), 2 = bf16-split store.
// R7 pipelined staging (verified: no spill at 84 VGPR, helped 97->67 us).
template<int ACT, int OUT>
__global__ __launch_bounds__(256) void gemm_bf16x2_kernel(
    const unsigned short* __restrict__ Ahi, const unsigned short* __restrict__ Alo,
    const unsigned short* __restrict__ Bhi, const unsigned short* __restrict__ Blo,
    const float* __restrict__ bias, float* __restrict__ C,
    unsigned short* __restrict__ Chi, unsigned short* __restrict__ Clo,
    int K, int lda, int ldb, int ldc)
{
  __shared__ unsigned short As[2][128][40];
  __shared__ unsigned short Bs[2][128][40];
  const int tid = threadIdx.x;
  const int m0 = blockIdx.y * 128;
  const int n0 = blockIdx.x * 128;
  const int w = tid >> 6, lane = tid & 63;
  const int wm = (w & 1) * 64, wn = (w >> 1) * 64;
  const int fm = lane & 15, fq = lane >> 4;
  const int r = tid >> 1, h = tid & 1;

  const unsigned short* pAh = Ahi + (size_t)(m0 + r) * lda + h * 16;
  const unsigned short* pAl = Alo + (size_t)(m0 + r) * lda + h * 16;
  const unsigned short* pBh = Bhi + (size_t)(n0 + r) * ldb + h * 16;
  const unsigned short* pBl = Blo + (size_t)(n0 + r) * ldb + h * 16;

  v4f acc[4][4];
#pragma unroll
  for (int i = 0; i < 4; i++)
#pragma unroll
    for (int j = 0; j < 4; j++) acc[i][j] = (v4f){0.f, 0.f, 0.f, 0.f};

  uint4 ah0 = *(const uint4*)(pAh),     ah1 = *(const uint4*)(pAh + 8);
  uint4 al0 = *(const uint4*)(pAl),     al1 = *(const uint4*)(pAl + 8);
  uint4 bh0 = *(const uint4*)(pBh),     bh1 = *(const uint4*)(pBh + 8);
  uint4 bl0 = *(const uint4*)(pBl),     bl1 = *(const uint4*)(pBl + 8);

  for (int k0 = 0; k0 < K; k0 += 32) {
    __syncthreads();
    *(uint4*)&As[0][r][h * 16]     = ah0;
    *(uint4*)&As[0][r][h * 16 + 8] = ah1;
    *(uint4*)&As[1][r][h * 16]     = al0;
    *(uint4*)&As[1][r][h * 16 + 8] = al1;
    *(uint4*)&Bs[0][r][h * 16]     = bh0;
    *(uint4*)&Bs[0][r][h * 16 + 8] = bh1;
    *(uint4*)&Bs[1][r][h * 16]     = bl0;
    *(uint4*)&Bs[1][r][h * 16 + 8] = bl1;
    __syncthreads();

    if (k0 + 32 < K) {
      int kn = k0 + 32;
      ah0 = *(const uint4*)(pAh + kn); ah1 = *(const uint4*)(pAh + kn + 8);
      al0 = *(const uint4*)(pAl + kn); al1 = *(const uint4*)(pAl + kn + 8);
      bh0 = *(const uint4*)(pBh + kn); bh1 = *(const uint4*)(pBh + kn + 8);
      bl0 = *(const uint4*)(pBl + kn); bl1 = *(const uint4*)(pBl + kn + 8);
    }

    v8s ah[4], al[4];
#pragma unroll
    for (int i = 0; i < 4; i++) {
      ah[i] = *(const v8s*)&As[0][wm + i * 16 + fm][fq * 8];
      al[i] = *(const v8s*)&As[1][wm + i * 16 + fm][fq * 8];
    }
#pragma unroll
    for (int j = 0; j < 4; j++) {
      v8s bh = *(const v8s*)&Bs[0][wn + j * 16 + fm][fq * 8];
      v8s bl = *(const v8s*)&Bs[1][wn + j * 16 + fm][fq * 8];
#pragma unroll
      for (int i = 0; i < 4; i++) {
        acc[i][j] = __builtin_amdgcn_mfma_f32_16x16x32_bf16(ah[i], bh, acc[i][j], 0, 0, 0);
        acc[i][j] = __builtin_amdgcn_mfma_f32_16x16x32_bf16(ah[i], bl, acc[i][j], 0, 0, 0);
        acc[i][j] = __builtin_amdgcn_mfma_f32_16x16x32_bf16(al[i], bh, acc[i][j], 0, 0, 0);
      }
    }
  }

#pragma unroll
  for (int i = 0; i < 4; i++)
#pragma unroll
    for (int j = 0; j < 4; j++) {
      int col = n0 + wn + j * 16 + fm;
      float bv = bias ? bias[col] : 0.0f;
#pragma unroll
      for (int reg = 0; reg < 4; reg++) {
        int row = m0 + wm + i * 16 + fq * 4 + reg;
        float v = acc[i][j][reg] + bv;
        v = act_apply<ACT>(v);
        size_t idx = (size_t)row * ldc + col;
        if (OUT == 0) C[idx] = v;
        else { unsigned short hi, lo; bfsplit(v, hi, lo); Chi[idx] = hi; Clo[idx] = lo; }
      }
    }
}

// ------- fused GEMM(bf16x2) + residual + LayerNorm + split write ---------------
// R10: tile 64 rows x 256 cols, 512 thr (8 waves, each 64 rows x 32 cols).
// Doubles MFMA per barrier vs the 32-row tile at same B-staging volume.
// Staging stays R7-style (load->store immediately, nothing live across barriers).
__global__ __launch_bounds__(512) void gemm_ln_kernel(
    const unsigned short* __restrict__ Ahi, const unsigned short* __restrict__ Alo,
    const unsigned short* __restrict__ Bhi, const unsigned short* __restrict__ Blo,
    const float* __restrict__ bias,
    const float* __restrict__ g, const float* __restrict__ beta,
    unsigned short* __restrict__ Xhi, unsigned short* __restrict__ Xlo,
    int K, int lda, int ldb)
{
  __shared__ unsigned short As[2][64][40];
  __shared__ unsigned short Bs[2][256][40];
  __shared__ float rs[64][9];
  __shared__ float ms[64][2];
  const int tid = threadIdx.x;
  const int m0 = blockIdx.x * 64;
  const int w = tid >> 6, lane = tid & 63;   // w in [0,8)
  const int fm = lane & 15, fq = lane >> 4;
  // A staging: 512 slots (2 planes x 64 rows x 4 chunks), 1/thread
  const int a_pl  = tid >> 8;
  const int a_row = (tid >> 2) & 63;
  const int a_c   = tid & 3;
  // B staging: 2048 slots, 4/thread (row halves x planes)
  const int b_row = tid >> 2;   // [0,128)
  const int b_c   = tid & 3;

  v4f acc[4][2];
#pragma unroll
  for (int i = 0; i < 4; i++)
#pragma unroll
    for (int j = 0; j < 2; j++) acc[i][j] = (v4f){0.f, 0.f, 0.f, 0.f};

  for (int k0 = 0; k0 < K; k0 += 32) {
    __syncthreads();
    {
      const unsigned short* asrc = (a_pl ? Alo : Ahi) + (size_t)(m0 + a_row) * lda + k0 + a_c * 8;
      *(uint4*)&As[a_pl][a_row][a_c * 8] = *(const uint4*)asrc;
    }
    *(uint4*)&Bs[0][b_row      ][b_c * 8] = *(const uint4*)(Bhi + (size_t)(b_row      ) * ldb + k0 + b_c * 8);
    *(uint4*)&Bs[0][b_row + 128][b_c * 8] = *(const uint4*)(Bhi + (size_t)(b_row + 128) * ldb + k0 + b_c * 8);
    *(uint4*)&Bs[1][b_row      ][b_c * 8] = *(const uint4*)(Blo + (size_t)(b_row      ) * ldb + k0 + b_c * 8);
    *(uint4*)&Bs[1][b_row + 128][b_c * 8] = *(const uint4*)(Blo + (size_t)(b_row + 128) * ldb + k0 + b_c * 8);
    __syncthreads();

    v8s ah[4], al[4];
#pragma unroll
    for (int i = 0; i < 4; i++) {
      ah[i] = *(const v8s*)&As[0][i * 16 + fm][fq * 8];
      al[i] = *(const v8s*)&As[1][i * 16 + fm][fq * 8];
    }
#pragma unroll
    for (int j = 0; j < 2; j++) {
      v8s bhf = *(const v8s*)&Bs[0][w * 32 + j * 16 + fm][fq * 8];
      v8s blf = *(const v8s*)&Bs[1][w * 32 + j * 16 + fm][fq * 8];
#pragma unroll
      for (int i = 0; i < 4; i++) {
        acc[i][j] = __builtin_amdgcn_mfma_f32_16x16x32_bf16(ah[i], bhf, acc[i][j], 0, 0, 0);
        acc[i][j] = __builtin_amdgcn_mfma_f32_16x16x32_bf16(ah[i], blf, acc[i][j], 0, 0, 0);
        acc[i][j] = __builtin_amdgcn_mfma_f32_16x16x32_bf16(al[i], bhf, acc[i][j], 0, 0, 0);
      }
    }
  }

  // acc <- x_old + delta + bias
#pragma unroll
  for (int i = 0; i < 4; i++)
#pragma unroll
    for (int j = 0; j < 2; j++) {
      int cl = w * 32 + j * 16 + fm;
      float bv = bias[cl];
#pragma unroll
      for (int reg = 0; reg < 4; reg++) {
        int rl = i * 16 + fq * 4 + reg;
        size_t idx = (size_t)(m0 + rl) * 256 + cl;
        acc[i][j][reg] += bv + bf2f(Xhi[idx]) + bf2f(Xlo[idx]);
      }
    }
  // mean
#pragma unroll
  for (int i = 0; i < 4; i++)
#pragma unroll
    for (int reg = 0; reg < 4; reg++) {
      float s = acc[i][0][reg] + acc[i][1][reg];
      s += __shfl_xor(s, 1); s += __shfl_xor(s, 2);
      s += __shfl_xor(s, 4); s += __shfl_xor(s, 8);
      if (fm == 0) rs[i * 16 + fq * 4 + reg][w] = s;
    }
  __syncthreads();
  if (tid < 64) {
    float s = 0.0f;
#pragma unroll
    for (int q = 0; q < 8; q++) s += rs[tid][q];
    ms[tid][0] = s * (1.0f / 256.0f);
  }
  __syncthreads();
  // var
#pragma unroll
  for (int i = 0; i < 4; i++)
#pragma unroll
    for (int reg = 0; reg < 4; reg++) {
      int rl = i * 16 + fq * 4 + reg;
      float mean = ms[rl][0];
      float d0 = acc[i][0][reg] - mean;
      float d1 = acc[i][1][reg] - mean;
      float s = d0 * d0 + d1 * d1;
      s += __shfl_xor(s, 1); s += __shfl_xor(s, 2);
      s += __shfl_xor(s, 4); s += __shfl_xor(s, 8);
      if (fm == 0) rs[rl][w] = s;
    }
  __syncthreads();
  if (tid < 64) {
    float s = 0.0f;
#pragma unroll
    for (int q = 0; q < 8; q++) s += rs[tid][q];
    ms[tid][1] = rsqrtf(s * (1.0f / 256.0f) + 1e-5f);
  }
  __syncthreads();
#pragma unroll
  for (int i = 0; i < 4; i++)
#pragma unroll
    for (int j = 0; j < 2; j++) {
      int cl = w * 32 + j * 16 + fm;
      float gv = g[cl], bv = beta[cl];
#pragma unroll
      for (int reg = 0; reg < 4; reg++) {
        int rl = i * 16 + fq * 4 + reg;
        float t = (acc[i][j][reg] - ms[rl][0]) * ms[rl][1] * gv + bv;
        size_t idx = (size_t)(m0 + rl) * 256 + cl;
        unsigned short hi, lo; bfsplit(t, hi, lo);
        Xhi[idx] = hi; Xlo[idx] = lo;
      }
    }
}

// -------- weight transpose + split (batched over layers via blockIdx.z) --------
__global__ __launch_bounds__(256) void wsplit_kernel(
    const float* __restrict__ W, unsigned short* __restrict__ Whi,
    unsigned short* __restrict__ Wlo, int K, int N, size_t wstride, size_t ostride)
{
  __shared__ float tile[32][33];
  const float* Wl = W + blockIdx.z * wstride;
  unsigned short* Whl = Whi + blockIdx.z * ostride;
  unsigned short* Wll = Wlo + blockIdx.z * ostride;
  int k0 = blockIdx.y * 32, n0 = blockIdx.x * 32;
  int t = threadIdx.x;
  int tn = t & 31, tk8 = t >> 5;
#pragma unroll
  for (int i = 0; i < 4; i++) {
    int k = tk8 + i * 8;
    tile[k][tn] = Wl[(size_t)(k0 + k) * N + n0 + tn];
  }
  __syncthreads();
  int tk = t & 31, tn8 = t >> 5;
#pragma unroll
  for (int i = 0; i < 4; i++) {
    int n = tn8 + i * 8;
    float v = tile[tk][n];
    unsigned short hi, lo; bfsplit(v, hi, lo);
    size_t idx = (size_t)(n0 + n) * K + k0 + tk;
    Whl[idx] = hi; Wll[idx] = lo;
  }
}

// ------------- fp32 GEMM 128x128 (embed only), POS + split write ---------------
template<int ACT, int POS, int SPLIT>
__global__ __launch_bounds__(256) void gemm128_kernel(
    const float* __restrict__ A, const float* __restrict__ W,
    const float* __restrict__ bias, const float* __restrict__ pos,
    float* __restrict__ C, unsigned short* __restrict__ Chi, unsigned short* __restrict__ Clo,
    int K, int lda, int ldw, int ldc)
{
  __shared__ float As[16][128];
  __shared__ float Ws[16][128];
  const int tid = threadIdx.x;
  const int m0 = blockIdx.y * 128;
  const int n0 = blockIdx.x * 128;
  const int tx = tid & 15, ty = tid >> 4;
  const int ar = tid >> 2, ak = (tid & 3) * 4;
  const int wk = tid >> 5, wn = (tid & 31) * 4;

  float acc[8][8];
#pragma unroll
  for (int i = 0; i < 8; i++)
#pragma unroll
    for (int j = 0; j < 8; j++) acc[i][j] = 0.0f;

  for (int k0 = 0; k0 < K; k0 += 16) {
    float4 a0 = *(const float4*)(A + (size_t)(m0 + ar)      * lda + k0 + ak);
    float4 a1 = *(const float4*)(A + (size_t)(m0 + ar + 64) * lda + k0 + ak);
    float4 w0 = *(const float4*)(W + (size_t)(k0 + wk)     * ldw + n0 + wn);
    float4 w1 = *(const float4*)(W + (size_t)(k0 + wk + 8) * ldw + n0 + wn);
    __syncthreads();
    As[ak + 0][ar] = a0.x; As[ak + 1][ar] = a0.y; As[ak + 2][ar] = a0.z; As[ak + 3][ar] = a0.w;
    As[ak + 0][ar + 64] = a1.x; As[ak + 1][ar + 64] = a1.y; As[ak + 2][ar + 64] = a1.z; As[ak + 3][ar + 64] = a1.w;
    *(float4*)&Ws[wk][wn] = w0;
    *(float4*)&Ws[wk + 8][wn] = w1;
    __syncthreads();
#pragma unroll
    for (int k = 0; k < 16; k++) {
      float4 xa = *(float4*)&As[k][ty * 8];
      float4 xb = *(float4*)&As[k][ty * 8 + 4];
      float4 y0 = *(float4*)&Ws[k][tx * 8];
      float4 y1 = *(float4*)&Ws[k][tx * 8 + 4];
      float a8[8] = {xa.x, xa.y, xa.z, xa.w, xb.x, xb.y, xb.z, xb.w};
      float b8[8] = {y0.x, y0.y, y0.z, y0.w, y1.x, y1.y, y1.z, y1.w};
#pragma unroll
      for (int i = 0; i < 8; i++)
#pragma unroll
        for (int j = 0; j < 8; j++) acc[i][j] = fmaf(a8[i], b8[j], acc[i][j]);
    }
  }
#pragma unroll
  for (int i = 0; i < 8; i++) {
    int row = m0 + ty * 8 + i;
    float* cp = C + (size_t)row * ldc + n0 + tx * 8;
    float v[8];
#pragma unroll
    for (int j = 0; j < 8; j++) {
      float t = acc[i][j];
      int col = n0 + tx * 8 + j;
      if (bias) t += bias[col];
      if (POS)  t += pos[(row & 63) * 256 + col];
      t = act_apply<ACT>(t);
      v[j] = t;
      if (SPLIT) {
        unsigned short hi, lo; bfsplit(t, hi, lo);
        size_t idx = (size_t)row * ldc + col;
        Chi[idx] = hi; Clo[idx] = lo;
      }
    }
    *(float4*)cp       = make_float4(v[0], v[1], v[2], v[3]);
    *(float4*)(cp + 4) = make_float4(v[4], v[5], v[6], v[7]);
  }
}

// ---------------- GEMM 64x64 tile fp32 (mamba), pipelined ----------------
template<int ACT>
__global__ __launch_bounds__(256) void gemm64_kernel(
    const float* __restrict__ A, const float* __restrict__ W,
    const float* __restrict__ bias, float* __restrict__ C,
    int K, int lda, int ldw, int ldc)
{
  __shared__ float As[16][64];
  __shared__ float Ws[16][64];
  const int tid = threadIdx.x;
  const int m0 = blockIdx.y * 64;
  const int n0 = blockIdx.x * 64;
  const int tx = tid & 15, ty = tid >> 4;
  const int ar = tid >> 2, ak = (tid & 3) * 4;
  const int wk = tid >> 4, wn = (tid & 15) * 4;

  float acc[4][4];
#pragma unroll
  for (int i = 0; i < 4; i++)
#pragma unroll
    for (int j = 0; j < 4; j++) acc[i][j] = 0.0f;

  float4 a0 = *(const float4*)(A + (size_t)(m0 + ar) * lda + ak);
  float4 w0 = *(const float4*)(W + (size_t)wk * ldw + n0 + wn);

  for (int k0 = 0; k0 < K; k0 += 16) {
    __syncthreads();
    As[ak + 0][ar] = a0.x; As[ak + 1][ar] = a0.y; As[ak + 2][ar] = a0.z; As[ak + 3][ar] = a0.w;
    *(float4*)&Ws[wk][wn] = w0;
    __syncthreads();
    if (k0 + 16 < K) {
      a0 = *(const float4*)(A + (size_t)(m0 + ar) * lda + k0 + 16 + ak);
      w0 = *(const float4*)(W + (size_t)(k0 + 16 + wk) * ldw + n0 + wn);
    }
#pragma unroll
    for (int k = 0; k < 16; k++) {
      float4 xa = *(float4*)&As[k][ty * 4];
      float4 yb = *(float4*)&Ws[k][tx * 4];
      float a4[4] = {xa.x, xa.y, xa.z, xa.w};
      float b4[4] = {yb.x, yb.y, yb.z, yb.w};
#pragma unroll
      for (int i = 0; i < 4; i++)
#pragma unroll
        for (int j = 0; j < 4; j++) acc[i][j] = fmaf(a4[i], b4[j], acc[i][j]);
    }
  }
#pragma unroll
  for (int i = 0; i < 4; i++) {
    float* cp = C + (size_t)(m0 + ty * 4 + i) * ldc + n0 + tx * 4;
    float v[4];
#pragma unroll
    for (int j = 0; j < 4; j++) {
      float t = acc[i][j];
      if (bias) t += bias[n0 + tx * 4 + j];
      v[j] = act_apply<ACT>(t);
    }
    *(float4*)cp = make_float4(v[0], v[1], v[2], v[3]);
  }
}

// ---------------- fused attention; writes bf16-split AT ----------------
// R10: Pt overlays Qt+Kt (dead after QK pass; single wave => lockstep-safe).
// LDS 44 KB -> 27 KB, occupancy 3 -> 5 single-wave blocks/CU.
__global__ __launch_bounds__(64) void attn_fused_kernel(
    const float* __restrict__ QKVc, const float* __restrict__ mask,
    unsigned short* __restrict__ AThi, unsigned short* __restrict__ ATlo, int n0)
{
  int bid = blockIdx.x;
  int nl = bid >> 3;
  int h = bid & 7;
  int n = n0 + nl;
  int tid = threadIdx.x;
  int tx = tid & 7, ty = tid >> 3;
  __shared__ float QKP[4352];          // Qt[32][68] | Kt[32][68]  ==  Pt[64][68]
  float (*Qt)[68] = (float(*)[68])QKP;
  float (*Kt)[68] = (float(*)[68])(QKP + 32 * 68);
  float (*Pt)[68] = (float(*)[68])QKP; // overlay
  __shared__ float Vs[64][36];
  __shared__ float bs[64];
  const float* base = QKVc + (size_t)nl * (64 * 768);
#pragma unroll
  for (int i = 0; i < 32; i++) {
    int idx = tid + i * 64;
    int bar = idx >> 5, c = idx & 31;
    Qt[c][bar] = base[bar * 768 + h * 32 + c];
    Kt[c][bar] = base[bar * 768 + 256 + h * 32 + c];
    Vs[bar][c] = base[bar * 768 + 512 + h * 32 + c];
  }
  bs[tid] = (1.0f - mask[n * 64 + tid]) * -1e9f;
  __syncthreads();
  float acc[8][8] = {};
  for (int c = 0; c < 32; c++) {
    float4 ax = *(float4*)&Qt[c][ty * 8];
    float4 ay = *(float4*)&Qt[c][ty * 8 + 4];
    float4 bx = *(float4*)&Kt[c][tx * 8];
    float4 by = *(float4*)&Kt[c][tx * 8 + 4];
    float a8[8] = {ax.x, ax.y, ax.z, ax.w, ay.x, ay.y, ay.z, ay.w};
    float b8[8] = {bx.x, bx.y, bx.z, bx.w, by.x, by.y, by.z, by.w};
#pragma unroll
    for (int i = 0; i < 8; i++)
#pragma unroll
      for (int j = 0; j < 8; j++) acc[i][j] = fmaf(a8[i], b8[j], acc[i][j]);
  }
  __syncthreads();   // Qt/Kt reads complete before Pt overlay writes
  const float scale = 0.17677669529663687f;
#pragma unroll
  for (int i = 0; i < 8; i++) {
    float s[8];
    float mx = -3.0e38f;
#pragma unroll
    for (int j = 0; j < 8; j++) { s[j] = acc[i][j] * scale + bs[tx * 8 + j]; mx = fmaxf(mx, s[j]); }
#pragma unroll
    for (int off = 1; off < 8; off <<= 1) mx = fmaxf(mx, __shfl_xor(mx, off));
    float sum = 0.0f;
#pragma unroll
    for (int j = 0; j < 8; j++) { s[j] = expf(s[j] - mx); sum += s[j]; }
#pragma unroll
    for (int off = 1; off < 8; off <<= 1) sum += __shfl_xor(sum, off);
    float inv = 1.0f / sum;
#pragma unroll
    for (int j = 0; j < 8; j++) Pt[tx * 8 + j][ty * 8 + i] = s[j] * inv;
  }
  __syncthreads();
  float o[8][4] = {};
  for (int j = 0; j < 64; j++) {
    float4 px = *(float4*)&Pt[j][ty * 8];
    float4 py = *(float4*)&Pt[j][ty * 8 + 4];
    float4 v  = *(float4*)&Vs[j][tx * 4];
    float p8[8] = {px.x, px.y, px.z, px.w, py.x, py.y, py.z, py.w};
#pragma unroll
    for (int i = 0; i < 8; i++) {
      o[i][0] = fmaf(p8[i], v.x, o[i][0]);
      o[i][1] = fmaf(p8[i], v.y, o[i][1]);
      o[i][2] = fmaf(p8[i], v.z, o[i][2]);
      o[i][3] = fmaf(p8[i], v.w, o[i][3]);
    }
  }
#pragma unroll
  for (int i = 0; i < 8; i++) {
    size_t base_o = (size_t)(nl * 64 + ty * 8 + i) * 256 + h * 32 + tx * 4;
#pragma unroll
    for (int c = 0; c < 4; c++) {
      unsigned short hi, lo; bfsplit(o[i][c], hi, lo);
      AThi[base_o + c] = hi; ATlo[base_o + c] = lo;
    }
  }
}

// ---------------- LayerNorm wave-per-row (mamba): o = LN(a)*g+beta + b ----------
__global__ __launch_bounds__(256) void ln_res_kernel(
    const float* __restrict__ a, const float* __restrict__ b,
    const float* __restrict__ g, const float* __restrict__ beta,
    float* __restrict__ o, int Wd)
{
  int wave = threadIdx.x >> 6;
  int lane = threadIdx.x & 63;
  int row = blockIdx.x * 4 + wave;
  int P = Wd >> 6;
  const float* ar = a + (size_t)row * Wd;
  const float* br = b + (size_t)row * Wd;
  float v[8];
  float s = 0.0f;
  for (int i = 0; i < P; i++) { float x = ar[lane + i * 64]; v[i] = x; s += x; }
#pragma unroll
  for (int off = 32; off; off >>= 1) s += __shfl_xor(s, off);
  float mean = s / Wd;
  float vs = 0.0f;
  for (int i = 0; i < P; i++) { float d = v[i] - mean; vs += d * d; }
#pragma unroll
  for (int off = 32; off; off >>= 1) vs += __shfl_xor(vs, off);
  float rstd = rsqrtf(vs / Wd + 1e-5f);
  for (int i = 0; i < P; i++) {
    int col = lane + i * 64;
    o[(size_t)row * Wd + col] = (v[i] - mean) * rstd * g[col] + beta[col] + br[col];
  }
}

// ------------- masked mean over bars (reads hi/lo X) ---------------------------
__global__ __launch_bounds__(256) void mean_kernel(
    const unsigned short* __restrict__ Xhi, const unsigned short* __restrict__ Xlo,
    const float* __restrict__ mask, float* __restrict__ FE, int n0)
{
  int n = blockIdx.x;
  int c = threadIdx.x;
  float s = 0.0f, ms = 0.0f;
  for (int bar = 0; bar < 64; bar++) {
    float mk = mask[(n0 + n) * 64 + bar];
    size_t idx = (size_t)(n * 64 + bar) * 256 + c;
    s = fmaf(bf2f(Xhi[idx]) + bf2f(Xlo[idx]), mk, s);
    ms += mk;
  }
  FE[(n0 + n) * 256 + c] = s / fmaxf(ms, 1.0f);
}

// ---------------- mamba conv (4-tap causal) + silu ----------------
__global__ __launch_bounds__(256) void conv_kernel(
    const float* __restrict__ XZ, const float* __restrict__ w,
    const float* __restrict__ b, float* __restrict__ XC)
{
  int idx = blockIdx.x * 256 + threadIdx.x;
  int t = idx >> 10, c = idx & 1023;
  float acc = b[c];
  const float* wc = w + c * 4;
#pragma unroll
  for (int k = 0; k < 4; k++) {
    int tt = t + k - 3;
    if (tt >= 0) acc = fmaf(XZ[(size_t)tt * 2048 + c], wc[k], acc);
  }
  XC[idx] = acc / (1.0f + expf(-acc));
}

// ---------------- chunked scan (32 chunks x 32 steps) ----------------
#define NCH 32
#define CLEN 32

__global__ __launch_bounds__(256) void scan1_kernel(
    const float* __restrict__ DT, const float* __restrict__ XC,
    const float* __restrict__ XDBL, const float* __restrict__ Alog,
    float* __restrict__ HEND, float* __restrict__ PPR)
{
  int j = blockIdx.x >> 2;
  int c = (blockIdx.x & 3) * 256 + threadIdx.x;
  int t0 = j * CLEN;
  __shared__ float Bs[CLEN][16];
  for (int i = threadIdx.x; i < CLEN * 16; i += 256) {
    int r = i >> 4, s = i & 15;
    Bs[r][s] = XDBL[(t0 + r) * 64 + 32 + s];
  }
  float A[16], h[16], Pp[16];
#pragma unroll
  for (int s = 0; s < 16; s++) {
    A[s] = -expf(Alog[c * 16 + s]);
    h[s] = 0.0f; Pp[s] = 1.0f;
  }
  __syncthreads();
  for (int tt = 0; tt < CLEN; tt++) {
    int t = t0 + tt;
    float dtv = DT[(size_t)t * 1024 + c];
    float u = dtv * XC[(size_t)t * 1024 + c];
#pragma unroll
    for (int s = 0; s < 16; s++) {
      float e = expf(dtv * A[s]);
      h[s] = fmaf(h[s], e, u * Bs[tt][s]);
      Pp[s] *= e;
    }
  }
#pragma unroll
  for (int s = 0; s < 16; s++) {
    HEND[(size_t)(j * 1024 + c) * 16 + s] = h[s];
    PPR [(size_t)(j * 1024 + c) * 16 + s] = Pp[s];
  }
}

__global__ __launch_bounds__(256) void scan2_kernel(
    const float* __restrict__ HEND, const float* __restrict__ PPR, float* __restrict__ CIN)
{
  int id = blockIdx.x * 256 + threadIdx.x;
  float carry = 0.0f;
  for (int j = 0; j < NCH; j++) {
    CIN[j * 16384 + id] = carry;
    carry = fmaf(PPR[j * 16384 + id], carry, HEND[j * 16384 + id]);
  }
}

__global__ __launch_bounds__(256) void scan3_kernel(
    const float* __restrict__ DT, const float* __restrict__ XC,
    const float* __restrict__ XDBL, const float* __restrict__ Alog,
    const float* __restrict__ CIN, const float* __restrict__ mD,
    const float* __restrict__ XZ, float* __restrict__ Y)
{
  int j = blockIdx.x >> 2;
  int c = (blockIdx.x & 3) * 256 + threadIdx.x;
  int t0 = j * CLEN;
  __shared__ float Bs[CLEN][16], Cs[CLEN][16];
  for (int i = threadIdx.x; i < CLEN * 16; i += 256) {
    int r = i >> 4, s = i & 15;
    Bs[r][s] = XDBL[(t0 + r) * 64 + 32 + s];
    Cs[r][s] = XDBL[(t0 + r) * 64 + 48 + s];
  }
  float A[16], h[16];
#pragma unroll
  for (int s = 0; s < 16; s++) {
    A[s] = -expf(Alog[c * 16 + s]);
    h[s] = CIN[(size_t)(j * 1024 + c) * 16 + s];
  }
  float dval = mD[c];
  __syncthreads();
  for (int tt = 0; tt < CLEN; tt++) {
    int t = t0 + tt;
    float dtv = DT[(size_t)t * 1024 + c];
    float xcv = XC[(size_t)t * 1024 + c];
    float u = dtv * xcv;
    float y = 0.0f;
#pragma unroll
    for (int s = 0; s < 16; s++) {
      float e = expf(dtv * A[s]);
      h[s] = fmaf(h[s], e, u * Bs[tt][s]);
      y = fmaf(h[s], Cs[tt][s], y);
    }
    float z = XZ[(size_t)t * 2048 + 1024 + c];
    float sz = z / (1.0f + expf(-z));
    Y[(size_t)t * 1024 + c] = (y + dval * xcv) * sz;
  }
}

// ---------------- pooling + head ----------------
__global__ __launch_bounds__(1024) void pool1_kernel(
    const float* __restrict__ XM, const float* __restrict__ pw,
    const float* __restrict__ pb, float* __restrict__ PW)
{
  int t = threadIdx.x;
  float s = pb[0];
  for (int i = 0; i < 512; i++) s = fmaf(XM[(size_t)t * 512 + i], pw[i], s);
  __shared__ float red[1024];
  red[t] = s;
  __syncthreads();
  for (int off = 512; off > 0; off >>= 1) {
    if (t < off) red[t] = fmaxf(red[t], red[t + off]);
    __syncthreads();
  }
  float mx = red[0];
  __syncthreads();
  float e = expf(s - mx);
  red[t] = e;
  __syncthreads();
  for (int off = 512; off > 0; off >>= 1) {
    if (t < off) red[t] = red[t] + red[t + off];
    __syncthreads();
  }
  PW[t] = e / red[0];
}

__global__ __launch_bounds__(256) void pool2_kernel(
    const float* __restrict__ XM, const float* __restrict__ PW, float* __restrict__ HP)
{
  int hcol = blockIdx.x * 256 + threadIdx.x;
  float s = 0.0f;
  for (int tn = 0; tn < 1024; tn++) s = fmaf(PW[tn], XM[(size_t)tn * 512 + hcol], s);
  HP[hcol] = s;
}

__device__ __forceinline__ float blk_reduce_sum_128(float v, float* red){
  int t = threadIdx.x;
#pragma unroll
  for (int off = 32; off; off >>= 1) v += __shfl_xor(v, off);
  __syncthreads();
  if ((t & 63) == 0) red[t >> 6] = v;
  __syncthreads();
  return red[0] + red[1];
}

__global__ __launch_bounds__(128) void head_kernel(
    const float* __restrict__ HP, const float* __restrict__ h1w, const float* __restrict__ h1b,
    const float* __restrict__ g1, const float* __restrict__ be1,
    const float* __restrict__ h2w, const float* __restrict__ h2b,
    const float* __restrict__ g2, const float* __restrict__ be2,
    const float* __restrict__ h3w, const float* __restrict__ h3b,
    float* __restrict__ out)
{
  __shared__ float t1[128];
  __shared__ float red[2];
  int i = threadIdx.x;
  float s = h1b[i];
  for (int k = 0; k < 512; k++) s = fmaf(HP[k], h1w[k * 128 + i], s);
  float mean = blk_reduce_sum_128(s, red) * (1.0f / 128.0f);
  float d = s - mean;
  float var = blk_reduce_sum_128(d * d, red) * (1.0f / 128.0f);
  float x1 = d * rsqrtf(var + 1e-5f) * g1[i] + be1[i];
  x1 = 0.5f * x1 * (1.0f + erff(x1 * 0.70710678118654752f));
  t1[i] = x1;
  __syncthreads();
  s = h2b[i];
  for (int k = 0; k < 128; k++) s = fmaf(t1[k], h2w[k * 128 + i], s);
  mean = blk_reduce_sum_128(s, red) * (1.0f / 128.0f);
  d = s - mean;
  var = blk_reduce_sum_128(d * d, red) * (1.0f / 128.0f);
  float x2 = d * rsqrtf(var + 1e-5f) * g2[i] + be2[i];
  x2 = 0.5f * x2 * (1.0f + erff(x2 * 0.70710678118654752f));
  float tot = blk_reduce_sum_128(x2 * h3w[i], red);
  if (i == 0) out[0] = tot + h3b[0];
}

__global__ __launch_bounds__(256) void copyx_kernel(const float* __restrict__ XM, float* __restrict__ out){
  int i = blockIdx.x * 256 + threadIdx.x;
  out[1 + i] = XM[i];
}

// ---------------- launch ----------------
extern "C" void kernel_launch(void* const* d_in, const int* in_sizes, int n_in,
                              void* d_out, int out_size, void* d_ws, size_t ws_size,
                              hipStream_t stream)
{
  const float* frames   = (const float*)d_in[0];
  const float* fmask    = (const float*)d_in[1];
  const float* in_w     = (const float*)d_in[2];
  const float* in_b     = (const float*)d_in[3];
  const float* pos_emb  = (const float*)d_in[4];
  const float* qkv_w    = (const float*)d_in[5];
  const float* qkv_b    = (const float*)d_in[6];
  const float* ao_w     = (const float*)d_in[7];
  const float* ao_b     = (const float*)d_in[8];
  const float* ln1_g    = (const float*)d_in[9];
  const float* ln1_b    = (const float*)d_in[10];
  const float* ffn_w1   = (const float*)d_in[11];
  const float* ffn_b1   = (const float*)d_in[12];
  const float* ffn_w2   = (const float*)d_in[13];
  const float* ffn_b2   = (const float*)d_in[14];
  const float* ln2_g    = (const float*)d_in[15];
  const float* ln2_b    = (const float*)d_in[16];
  const float* proj_w   = (const float*)d_in[17];
  const float* proj_b   = (const float*)d_in[18];
  const float* m_in_w   = (const float*)d_in[19];
  const float* m_conv_w = (const float*)d_in[20];
  const float* m_conv_b = (const float*)d_in[21];
  const float* m_xproj_w= (const float*)d_in[22];
  const float* m_dt_w   = (const float*)d_in[23];
  const float* m_dt_b   = (const float*)d_in[24];
  const float* m_Alog   = (const float*)d_in[25];
  const float* m_D      = (const float*)d_in[26];
  const float* m_out_w  = (const float*)d_in[27];
  const float* m_ln_g   = (const float*)d_in[28];
  const float* m_ln_b   = (const float*)d_in[29];
  const float* pool_w   = (const float*)d_in[30];
  const float* pool_b   = (const float*)d_in[31];
  const float* h1_w     = (const float*)d_in[32];
  const float* h1_b     = (const float*)d_in[33];
  const float* hg1      = (const float*)d_in[34];
  const float* hb1      = (const float*)d_in[35];
  const float* h2_w     = (const float*)d_in[36];
  const float* h2_b     = (const float*)d_in[37];
  const float* hg2      = (const float*)d_in[38];
  const float* hb2      = (const float*)d_in[39];
  const float* h3_w     = (const float*)d_in[40];
  const float* h3_b     = (const float*)d_in[41];
  float* out = (float*)d_out;

  // ---- workspace layout (floats), total 24,906,752 = 99.6 MB ----
  float* ws = (float*)d_ws;
  float* B  = ws;
  float* QF = B;                                       // 12,582,912 floats
  unsigned short* AThi = (unsigned short*)(B + 12582912);  // 4,194,304 shorts
  unsigned short* ATlo = AThi + 4194304;
  unsigned short* MIDhi = (unsigned short*)B;              // 16,777,216 shorts
  unsigned short* MIDlo = MIDhi + 16777216;

  unsigned short* Xhi = (unsigned short*)(ws + 16777216);  // 4,194,304 shorts
  unsigned short* Xlo = Xhi + 4194304;

  unsigned short* Wqkv_hi = (unsigned short*)(ws + 20971520); // 786,432
  unsigned short* Wqkv_lo = Wqkv_hi + 786432;
  unsigned short* Wao_hi  = Wqkv_lo + 786432;    // 262,144
  unsigned short* Wao_lo  = Wao_hi + 262144;
  unsigned short* Wf1_hi  = Wao_lo + 262144;     // 1,048,576
  unsigned short* Wf1_lo  = Wf1_hi + 1048576;
  unsigned short* Wf2_hi  = Wf1_lo + 1048576;    // 1,048,576
  unsigned short* Wf2_lo  = Wf2_hi + 1048576;    // ends at ws + 24,117,248 floats

  float* FE = ws + 24117248;         //   262,144
  float* XM = FE + 262144;           //   524,288
  float* PW = XM + 524288;           //     2,048
  float* HP = PW + 2048;             //     1,024

  // mamba aliases overlay B
  float* XZ   = B;                 // 2,097,152 (1024x2048)
  float* XC   = B + 2097152;       // 1,048,576
  float* DT   = B + 3145728;       // 1,048,576
  float* XDBL = B + 4194304;       //    65,536
  float* Y    = B + 4259840;       // 1,048,576
  float* TMP  = B + 5308416;       //   524,288
  float* HEND = B + 5832704;       //   524,288
  float* PPR  = B + 6356992;       //   524,288
  float* CIN  = B + 6881280;       //   524,288

  // ---- weight prep: 4 batched launches (z = layer) ----
  wsplit_kernel<<<dim3(24,8,4),256,0,stream>>>(qkv_w, Wqkv_hi, Wqkv_lo, 256, 768, 196608, 196608);
  wsplit_kernel<<<dim3(8,8,4),256,0,stream>>>(ao_w, Wao_hi, Wao_lo, 256, 256, 65536, 65536);
  wsplit_kernel<<<dim3(32,8,4),256,0,stream>>>(ffn_w1, Wf1_hi, Wf1_lo, 256, 1024, 262144, 262144);
  wsplit_kernel<<<dim3(8,32,4),256,0,stream>>>(ffn_w2, Wf2_hi, Wf2_lo, 1024, 256, 262144, 262144);

  // ---- encoder: 4 chunks of 256 sequences (16384 rows) ----
  for (int ch = 0; ch < 4; ch++) {
    int n0 = ch * 256;
    const float* fch = frames + (size_t)n0 * 64 * 32;
    gemm128_kernel<ACT_NONE,1,1><<<dim3(2,128),256,0,stream>>>(
        fch, in_w, in_b, pos_emb, QF, Xhi, Xlo, 32, 32, 256, 256);
    for (int l = 0; l < 4; l++) {
      gemm_bf16x2_kernel<ACT_NONE,0><<<dim3(6,128),256,0,stream>>>(
          Xhi, Xlo, Wqkv_hi + l*196608, Wqkv_lo + l*196608, qkv_b + l*768,
          QF, nullptr, nullptr, 256, 256, 256, 768);
      attn_fused_kernel<<<2048,64,0,stream>>>(QF, fmask, AThi, ATlo, n0);
      gemm_ln_kernel<<<256,512,0,stream>>>(
          AThi, ATlo, Wao_hi + l*65536, Wao_lo + l*65536, ao_b + l*256,
          ln1_g + l*256, ln1_b + l*256, Xhi, Xlo, 256, 256, 256);
      gemm_bf16x2_kernel<ACT_GELU,2><<<dim3(8,128),256,0,stream>>>(
          Xhi, Xlo, Wf1_hi + l*262144, Wf1_lo + l*262144, ffn_b1 + l*1024,
          nullptr, MIDhi, MIDlo, 256, 256, 256, 1024);
      gemm_ln_kernel<<<256,512,0,stream>>>(
          MIDhi, MIDlo, Wf2_hi + l*262144, Wf2_lo + l*262144, ffn_b2 + l*256,
          ln2_g + l*256, ln2_b + l*256, Xhi, Xlo, 1024, 1024, 1024);
    }
    mean_kernel<<<256,256,0,stream>>>(Xhi, Xlo, fmask, FE, n0);
  }

  gemm64_kernel<ACT_NONE><<<dim3(8,16),256,0,stream>>>(FE, proj_w, proj_b, XM, 256, 256, 512, 512);

  for (int l = 0; l < 8; l++) {
    gemm64_kernel<ACT_NONE><<<dim3(32,16),256,0,stream>>>(
        XM, m_in_w + (size_t)l*512*2048, nullptr, XZ, 512, 512, 2048, 2048);
    conv_kernel<<<4096,256,0,stream>>>(XZ, m_conv_w + l*1024*4, m_conv_b + l*1024, XC);
    gemm64_kernel<ACT_NONE><<<dim3(1,16),256,0,stream>>>(
        XC, m_xproj_w + (size_t)l*1024*64, nullptr, XDBL, 1024, 1024, 64, 64);
    gemm64_kernel<ACT_SOFTPLUS><<<dim3(16,16),256,0,stream>>>(
        XDBL, m_dt_w + (size_t)l*32*1024, m_dt_b + l*1024, DT, 32, 64, 1024, 1024);
    scan1_kernel<<<128,256,0,stream>>>(DT, XC, XDBL, m_Alog + l*16384, HEND, PPR);
    scan2_kernel<<<64,256,0,stream>>>(HEND, PPR, CIN);
    scan3_kernel<<<128,256,0,stream>>>(DT, XC, XDBL, m_Alog + l*16384, CIN, m_D + l*1024, XZ, Y);
    gemm64_kernel<ACT_NONE><<<dim3(8,16),256,0,stream>>>(
        Y, m_out_w + (size_t)l*1024*512, nullptr, TMP, 1024, 1024, 512, 512);
    ln_res_kernel<<<256,256,0,stream>>>(TMP, XM, m_ln_g + l*512, m_ln_b + l*512, XM, 512);
  }

  pool1_kernel<<<1,1024,0,stream>>>(XM, pool_w, pool_b, PW);
  pool2_kernel<<<2,256,0,stream>>>(XM, PW, HP);
  head_kernel<<<1,128,0,stream>>>(HP, h1_w, h1_b, hg1, hb1, h2_w, h2_b, hg2, hb2, h3_w, h3_b, out);
  copyx_kernel<<<2048,256,0,stream>>>(XM, out);
}

// Round 11
// 5313.996 us; speedup vs baseline: 1.3913x; 1.0146x over previous
//
#include <hip/hip_runtime.h>
#include <math.h>

#define ACT_NONE 0
#define ACT_GELU 1
#define ACT_SOFTPLUS 2

template<int ACT>
__device__ __forceinline__ float act_apply(float x){
  if (ACT == ACT_GELU)     return 0.5f * x * (1.0f + erff(x * 0.70710678118654752f));
  if (ACT == ACT_SOFTPLUS) return fmaxf(x, 0.0f) + log1pf(expf(-fabsf(x)));
  return x;
}

// ---------------- bf16 split helpers ----------------
__device__ __forceinline__ unsigned short f2bf(float x){
  unsigned u = __float_as_uint(x);
  u = u + 0x7FFFu + ((u >> 16) & 1u);
  return (unsigned short)(u >> 16);
}
__device__ __forceinline__ float bf2f(unsigned short b){
  return __uint_as_float(((unsigned)b) << 16);
}
__device__ __forceinline__ void bfsplit(float x, unsigned short &hi, unsigned short &lo){
  hi = f2bf(x);
  lo = f2bf(x - bf2f(hi));
}

typedef __attribute__((ext_vector_type(8))) short v8s;
typedef __attribute__((ext_vector_type(4))) float v4f;

// ---------------- bf16x2 MFMA GEMM: 128x128 tile, 256 thr (4 waves) ------------
// R11: m-major grid — m0 = blockIdx.x so blocks sharing an A tile land on the
// same XCD (linear IDs differ by gridDim.x, a multiple of 8). Fixes 4x A
// over-fetch seen in R10 (FETCH 69 MB vs 18 MB compulsory).
template<int ACT, int OUT>
__global__ __launch_bounds__(256) void gemm_bf16x2_kernel(
    const unsigned short* __restrict__ Ahi, const unsigned short* __restrict__ Alo,
    const unsigned short* __restrict__ Bhi, const unsigned short* __restrict__ Blo,
    const float* __restrict__ bias, float* __restrict__ C,
    unsigned short* __restrict__ Chi, unsigned short* __restrict__ Clo,
    int K, int lda, int ldb, int ldc)
{
  __shared__ unsigned short As[2][128][40];
  __shared__ unsigned short Bs[2][128][40];
  const int tid = threadIdx.x;
  const int m0 = blockIdx.x * 128;
  const int n0 = blockIdx.y * 128;
  const int w = tid >> 6, lane = tid & 63;
  const int wm = (w & 1) * 64, wn = (w >> 1) * 64;
  const int fm = lane & 15, fq = lane >> 4;
  const int r = tid >> 1, h = tid & 1;

  const unsigned short* pAh = Ahi + (size_t)(m0 + r) * lda + h * 16;
  const unsigned short* pAl = Alo + (size_t)(m0 + r) * lda + h * 16;
  const unsigned short* pBh = Bhi + (size_t)(n0 + r) * ldb + h * 16;
  const unsigned short* pBl = Blo + (size_t)(n0 + r) * ldb + h * 16;

  v4f acc[4][4];
#pragma unroll
  for (int i = 0; i < 4; i++)
#pragma unroll
    for (int j = 0; j < 4; j++) acc[i][j] = (v4f){0.f, 0.f, 0.f, 0.f};

  uint4 ah0 = *(const uint4*)(pAh),     ah1 = *(const uint4*)(pAh + 8);
  uint4 al0 = *(const uint4*)(pAl),     al1 = *(const uint4*)(pAl + 8);
  uint4 bh0 = *(const uint4*)(pBh),     bh1 = *(const uint4*)(pBh + 8);
  uint4 bl0 = *(const uint4*)(pBl),     bl1 = *(const uint4*)(pBl + 8);

  for (int k0 = 0; k0 < K; k0 += 32) {
    __syncthreads();
    *(uint4*)&As[0][r][h * 16]     = ah0;
    *(uint4*)&As[0][r][h * 16 + 8] = ah1;
    *(uint4*)&As[1][r][h * 16]     = al0;
    *(uint4*)&As[1][r][h * 16 + 8] = al1;
    *(uint4*)&Bs[0][r][h * 16]     = bh0;
    *(uint4*)&Bs[0][r][h * 16 + 8] = bh1;
    *(uint4*)&Bs[1][r][h * 16]     = bl0;
    *(uint4*)&Bs[1][r][h * 16 + 8] = bl1;
    __syncthreads();

    if (k0 + 32 < K) {
      int kn = k0 + 32;
      ah0 = *(const uint4*)(pAh + kn); ah1 = *(const uint4*)(pAh + kn + 8);
      al0 = *(const uint4*)(pAl + kn); al1 = *(const uint4*)(pAl + kn + 8);
      bh0 = *(const uint4*)(pBh + kn); bh1 = *(const uint4*)(pBh + kn + 8);
      bl0 = *(const uint4*)(pBl + kn); bl1 = *(const uint4*)(pBl + kn + 8);
    }

    v8s ah[4], al[4];
#pragma unroll
    for (int i = 0; i < 4; i++) {
      ah[i] = *(const v8s*)&As[0][wm + i * 16 + fm][fq * 8];
      al[i] = *(const v8s*)&As[1][wm + i * 16 + fm][fq * 8];
    }
#pragma unroll
    for (int j = 0; j < 4; j++) {
      v8s bh = *(const v8s*)&Bs[0][wn + j * 16 + fm][fq * 8];
      v8s bl = *(const v8s*)&Bs[1][wn + j * 16 + fm][fq * 8];
#pragma unroll
      for (int i = 0; i < 4; i++) {
        acc[i][j] = __builtin_amdgcn_mfma_f32_16x16x32_bf16(ah[i], bh, acc[i][j], 0, 0, 0);
        acc[i][j] = __builtin_amdgcn_mfma_f32_16x16x32_bf16(ah[i], bl, acc[i][j], 0, 0, 0);
        acc[i][j] = __builtin_amdgcn_mfma_f32_16x16x32_bf16(al[i], bh, acc[i][j], 0, 0, 0);
      }
    }
  }

#pragma unroll
  for (int i = 0; i < 4; i++)
#pragma unroll
    for (int j = 0; j < 4; j++) {
      int col = n0 + wn + j * 16 + fm;
      float bv = bias ? bias[col] : 0.0f;
#pragma unroll
      for (int reg = 0; reg < 4; reg++) {
        int row = m0 + wm + i * 16 + fq * 4 + reg;
        float v = acc[i][j][reg] + bv;
        v = act_apply<ACT>(v);
        size_t idx = (size_t)row * ldc + col;
        if (OUT == 0) C[idx] = v;
        else { unsigned short hi, lo; bfsplit(v, hi, lo); Chi[idx] = hi; Clo[idx] = lo; }
      }
    }
}

// ------- fused GEMM(bf16x2) + residual + LayerNorm + split write ---------------
// tile 64 rows x 256 cols, 512 thr (R10 shape; staging R7-style, no spill).
__global__ __launch_bounds__(512) void gemm_ln_kernel(
    const unsigned short* __restrict__ Ahi, const unsigned short* __restrict__ Alo,
    const unsigned short* __restrict__ Bhi, const unsigned short* __restrict__ Blo,
    const float* __restrict__ bias,
    const float* __restrict__ g, const float* __restrict__ beta,
    unsigned short* __restrict__ Xhi, unsigned short* __restrict__ Xlo,
    int K, int lda, int ldb)
{
  __shared__ unsigned short As[2][64][40];
  __shared__ unsigned short Bs[2][256][40];
  __shared__ float rs[64][9];
  __shared__ float ms[64][2];
  const int tid = threadIdx.x;
  const int m0 = blockIdx.x * 64;
  const int w = tid >> 6, lane = tid & 63;
  const int fm = lane & 15, fq = lane >> 4;
  const int a_pl  = tid >> 8;
  const int a_row = (tid >> 2) & 63;
  const int a_c   = tid & 3;
  const int b_row = tid >> 2;
  const int b_c   = tid & 3;

  v4f acc[4][2];
#pragma unroll
  for (int i = 0; i < 4; i++)
#pragma unroll
    for (int j = 0; j < 2; j++) acc[i][j] = (v4f){0.f, 0.f, 0.f, 0.f};

  for (int k0 = 0; k0 < K; k0 += 32) {
    __syncthreads();
    {
      const unsigned short* asrc = (a_pl ? Alo : Ahi) + (size_t)(m0 + a_row) * lda + k0 + a_c * 8;
      *(uint4*)&As[a_pl][a_row][a_c * 8] = *(const uint4*)asrc;
    }
    *(uint4*)&Bs[0][b_row      ][b_c * 8] = *(const uint4*)(Bhi + (size_t)(b_row      ) * ldb + k0 + b_c * 8);
    *(uint4*)&Bs[0][b_row + 128][b_c * 8] = *(const uint4*)(Bhi + (size_t)(b_row + 128) * ldb + k0 + b_c * 8);
    *(uint4*)&Bs[1][b_row      ][b_c * 8] = *(const uint4*)(Blo + (size_t)(b_row      ) * ldb + k0 + b_c * 8);
    *(uint4*)&Bs[1][b_row + 128][b_c * 8] = *(const uint4*)(Blo + (size_t)(b_row + 128) * ldb + k0 + b_c * 8);
    __syncthreads();

    v8s ah[4], al[4];
#pragma unroll
    for (int i = 0; i < 4; i++) {
      ah[i] = *(const v8s*)&As[0][i * 16 + fm][fq * 8];
      al[i] = *(const v8s*)&As[1][i * 16 + fm][fq * 8];
    }
#pragma unroll
    for (int j = 0; j < 2; j++) {
      v8s bhf = *(const v8s*)&Bs[0][w * 32 + j * 16 + fm][fq * 8];
      v8s blf = *(const v8s*)&Bs[1][w * 32 + j * 16 + fm][fq * 8];
#pragma unroll
      for (int i = 0; i < 4; i++) {
        acc[i][j] = __builtin_amdgcn_mfma_f32_16x16x32_bf16(ah[i], bhf, acc[i][j], 0, 0, 0);
        acc[i][j] = __builtin_amdgcn_mfma_f32_16x16x32_bf16(ah[i], blf, acc[i][j], 0, 0, 0);
        acc[i][j] = __builtin_amdgcn_mfma_f32_16x16x32_bf16(al[i], bhf, acc[i][j], 0, 0, 0);
      }
    }
  }

#pragma unroll
  for (int i = 0; i < 4; i++)
#pragma unroll
    for (int j = 0; j < 2; j++) {
      int cl = w * 32 + j * 16 + fm;
      float bv = bias[cl];
#pragma unroll
      for (int reg = 0; reg < 4; reg++) {
        int rl = i * 16 + fq * 4 + reg;
        size_t idx = (size_t)(m0 + rl) * 256 + cl;
        acc[i][j][reg] += bv + bf2f(Xhi[idx]) + bf2f(Xlo[idx]);
      }
    }
#pragma unroll
  for (int i = 0; i < 4; i++)
#pragma unroll
    for (int reg = 0; reg < 4; reg++) {
      float s = acc[i][0][reg] + acc[i][1][reg];
      s += __shfl_xor(s, 1); s += __shfl_xor(s, 2);
      s += __shfl_xor(s, 4); s += __shfl_xor(s, 8);
      if (fm == 0) rs[i * 16 + fq * 4 + reg][w] = s;
    }
  __syncthreads();
  if (tid < 64) {
    float s = 0.0f;
#pragma unroll
    for (int q = 0; q < 8; q++) s += rs[tid][q];
    ms[tid][0] = s * (1.0f / 256.0f);
  }
  __syncthreads();
#pragma unroll
  for (int i = 0; i < 4; i++)
#pragma unroll
    for (int reg = 0; reg < 4; reg++) {
      int rl = i * 16 + fq * 4 + reg;
      float mean = ms[rl][0];
      float d0 = acc[i][0][reg] - mean;
      float d1 = acc[i][1][reg] - mean;
      float s = d0 * d0 + d1 * d1;
      s += __shfl_xor(s, 1); s += __shfl_xor(s, 2);
      s += __shfl_xor(s, 4); s += __shfl_xor(s, 8);
      if (fm == 0) rs[rl][w] = s;
    }
  __syncthreads();
  if (tid < 64) {
    float s = 0.0f;
#pragma unroll
    for (int q = 0; q < 8; q++) s += rs[tid][q];
    ms[tid][1] = rsqrtf(s * (1.0f / 256.0f) + 1e-5f);
  }
  __syncthreads();
#pragma unroll
  for (int i = 0; i < 4; i++)
#pragma unroll
    for (int j = 0; j < 2; j++) {
      int cl = w * 32 + j * 16 + fm;
      float gv = g[cl], bv = beta[cl];
#pragma unroll
      for (int reg = 0; reg < 4; reg++) {
        int rl = i * 16 + fq * 4 + reg;
        float t = (acc[i][j][reg] - ms[rl][0]) * ms[rl][1] * gv + bv;
        size_t idx = (size_t)(m0 + rl) * 256 + cl;
        unsigned short hi, lo; bfsplit(t, hi, lo);
        Xhi[idx] = hi; Xlo[idx] = lo;
      }
    }
}

// -------- weight transpose + split (batched over layers via blockIdx.z) --------
__global__ __launch_bounds__(256) void wsplit_kernel(
    const float* __restrict__ W, unsigned short* __restrict__ Whi,
    unsigned short* __restrict__ Wlo, int K, int N, size_t wstride, size_t ostride)
{
  __shared__ float tile[32][33];
  const float* Wl = W + blockIdx.z * wstride;
  unsigned short* Whl = Whi + blockIdx.z * ostride;
  unsigned short* Wll = Wlo + blockIdx.z * ostride;
  int k0 = blockIdx.y * 32, n0 = blockIdx.x * 32;
  int t = threadIdx.x;
  int tn = t & 31, tk8 = t >> 5;
#pragma unroll
  for (int i = 0; i < 4; i++) {
    int k = tk8 + i * 8;
    tile[k][tn] = Wl[(size_t)(k0 + k) * N + n0 + tn];
  }
  __syncthreads();
  int tk = t & 31, tn8 = t >> 5;
#pragma unroll
  for (int i = 0; i < 4; i++) {
    int n = tn8 + i * 8;
    float v = tile[tk][n];
    unsigned short hi, lo; bfsplit(v, hi, lo);
    size_t idx = (size_t)(n0 + n) * K + k0 + tk;
    Whl[idx] = hi; Wll[idx] = lo;
  }
}

// ------------- fp32 GEMM 128x128 (embed only), POS + split write ---------------
template<int ACT, int POS, int SPLIT>
__global__ __launch_bounds__(256) void gemm128_kernel(
    const float* __restrict__ A, const float* __restrict__ W,
    const float* __restrict__ bias, const float* __restrict__ pos,
    float* __restrict__ C, unsigned short* __restrict__ Chi, unsigned short* __restrict__ Clo,
    int K, int lda, int ldw, int ldc)
{
  __shared__ float As[16][128];
  __shared__ float Ws[16][128];
  const int tid = threadIdx.x;
  const int m0 = blockIdx.y * 128;
  const int n0 = blockIdx.x * 128;
  const int tx = tid & 15, ty = tid >> 4;
  const int ar = tid >> 2, ak = (tid & 3) * 4;
  const int wk = tid >> 5, wn = (tid & 31) * 4;

  float acc[8][8];
#pragma unroll
  for (int i = 0; i < 8; i++)
#pragma unroll
    for (int j = 0; j < 8; j++) acc[i][j] = 0.0f;

  for (int k0 = 0; k0 < K; k0 += 16) {
    float4 a0 = *(const float4*)(A + (size_t)(m0 + ar)      * lda + k0 + ak);
    float4 a1 = *(const float4*)(A + (size_t)(m0 + ar + 64) * lda + k0 + ak);
    float4 w0 = *(const float4*)(W + (size_t)(k0 + wk)     * ldw + n0 + wn);
    float4 w1 = *(const float4*)(W + (size_t)(k0 + wk + 8) * ldw + n0 + wn);
    __syncthreads();
    As[ak + 0][ar] = a0.x; As[ak + 1][ar] = a0.y; As[ak + 2][ar] = a0.z; As[ak + 3][ar] = a0.w;
    As[ak + 0][ar + 64] = a1.x; As[ak + 1][ar + 64] = a1.y; As[ak + 2][ar + 64] = a1.z; As[ak + 3][ar + 64] = a1.w;
    *(float4*)&Ws[wk][wn] = w0;
    *(float4*)&Ws[wk + 8][wn] = w1;
    __syncthreads();
#pragma unroll
    for (int k = 0; k < 16; k++) {
      float4 xa = *(float4*)&As[k][ty * 8];
      float4 xb = *(float4*)&As[k][ty * 8 + 4];
      float4 y0 = *(float4*)&Ws[k][tx * 8];
      float4 y1 = *(float4*)&Ws[k][tx * 8 + 4];
      float a8[8] = {xa.x, xa.y, xa.z, xa.w, xb.x, xb.y, xb.z, xb.w};
      float b8[8] = {y0.x, y0.y, y0.z, y0.w, y1.x, y1.y, y1.z, y1.w};
#pragma unroll
      for (int i = 0; i < 8; i++)
#pragma unroll
        for (int j = 0; j < 8; j++) acc[i][j] = fmaf(a8[i], b8[j], acc[i][j]);
    }
  }
#pragma unroll
  for (int i = 0; i < 8; i++) {
    int row = m0 + ty * 8 + i;
    float* cp = C + (size_t)row * ldc + n0 + tx * 8;
    float v[8];
#pragma unroll
    for (int j = 0; j < 8; j++) {
      float t = acc[i][j];
      int col = n0 + tx * 8 + j;
      if (bias) t += bias[col];
      if (POS)  t += pos[(row & 63) * 256 + col];
      t = act_apply<ACT>(t);
      v[j] = t;
      if (SPLIT) {
        unsigned short hi, lo; bfsplit(t, hi, lo);
        size_t idx = (size_t)row * ldc + col;
        Chi[idx] = hi; Clo[idx] = lo;
      }
    }
    *(float4*)cp       = make_float4(v[0], v[1], v[2], v[3]);
    *(float4*)(cp + 4) = make_float4(v[4], v[5], v[6], v[7]);
  }
}

// ---------------- GEMM 64x64 tile fp32 (mamba), pipelined; opt. split write ----
template<int ACT, int SPLIT>
__global__ __launch_bounds__(256) void gemm64_kernel(
    const float* __restrict__ A, const float* __restrict__ W,
    const float* __restrict__ bias, float* __restrict__ C,
    unsigned short* __restrict__ Chi, unsigned short* __restrict__ Clo,
    int K, int lda, int ldw, int ldc)
{
  __shared__ float As[16][64];
  __shared__ float Ws[16][64];
  const int tid = threadIdx.x;
  const int m0 = blockIdx.y * 64;
  const int n0 = blockIdx.x * 64;
  const int tx = tid & 15, ty = tid >> 4;
  const int ar = tid >> 2, ak = (tid & 3) * 4;
  const int wk = tid >> 4, wn = (tid & 15) * 4;

  float acc[4][4];
#pragma unroll
  for (int i = 0; i < 4; i++)
#pragma unroll
    for (int j = 0; j < 4; j++) acc[i][j] = 0.0f;

  float4 a0 = *(const float4*)(A + (size_t)(m0 + ar) * lda + ak);
  float4 w0 = *(const float4*)(W + (size_t)wk * ldw + n0 + wn);

  for (int k0 = 0; k0 < K; k0 += 16) {
    __syncthreads();
    As[ak + 0][ar] = a0.x; As[ak + 1][ar] = a0.y; As[ak + 2][ar] = a0.z; As[ak + 3][ar] = a0.w;
    *(float4*)&Ws[wk][wn] = w0;
    __syncthreads();
    if (k0 + 16 < K) {
      a0 = *(const float4*)(A + (size_t)(m0 + ar) * lda + k0 + 16 + ak);
      w0 = *(const float4*)(W + (size_t)(k0 + 16 + wk) * ldw + n0 + wn);
    }
#pragma unroll
    for (int k = 0; k < 16; k++) {
      float4 xa = *(float4*)&As[k][ty * 4];
      float4 yb = *(float4*)&Ws[k][tx * 4];
      float a4[4] = {xa.x, xa.y, xa.z, xa.w};
      float b4[4] = {yb.x, yb.y, yb.z, yb.w};
#pragma unroll
      for (int i = 0; i < 4; i++)
#pragma unroll
        for (int j = 0; j < 4; j++) acc[i][j] = fmaf(a4[i], b4[j], acc[i][j]);
    }
  }
#pragma unroll
  for (int i = 0; i < 4; i++) {
    int row = m0 + ty * 4 + i;
    float* cp = C + (size_t)row * ldc + n0 + tx * 4;
    float v[4];
#pragma unroll
    for (int j = 0; j < 4; j++) {
      float t = acc[i][j];
      if (bias) t += bias[n0 + tx * 4 + j];
      t = act_apply<ACT>(t);
      v[j] = t;
      if (SPLIT) {
        unsigned short hi, lo; bfsplit(t, hi, lo);
        size_t idx = (size_t)row * ldc + n0 + tx * 4 + j;
        Chi[idx] = hi; Clo[idx] = lo;
      }
    }
    *(float4*)cp = make_float4(v[0], v[1], v[2], v[3]);
  }
}

// ---------------- fused attention; writes bf16-split AT ----------------
__global__ __launch_bounds__(64) void attn_fused_kernel(
    const float* __restrict__ QKVc, const float* __restrict__ mask,
    unsigned short* __restrict__ AThi, unsigned short* __restrict__ ATlo, int n0)
{
  int bid = blockIdx.x;
  int nl = bid >> 3;
  int h = bid & 7;
  int n = n0 + nl;
  int tid = threadIdx.x;
  int tx = tid & 7, ty = tid >> 3;
  __shared__ float QKP[4352];
  float (*Qt)[68] = (float(*)[68])QKP;
  float (*Kt)[68] = (float(*)[68])(QKP + 32 * 68);
  float (*Pt)[68] = (float(*)[68])QKP;
  __shared__ float Vs[64][36];
  __shared__ float bs[64];
  const float* base = QKVc + (size_t)nl * (64 * 768);
#pragma unroll
  for (int i = 0; i < 32; i++) {
    int idx = tid + i * 64;
    int bar = idx >> 5, c = idx & 31;
    Qt[c][bar] = base[bar * 768 + h * 32 + c];
    Kt[c][bar] = base[bar * 768 + 256 + h * 32 + c];
    Vs[bar][c] = base[bar * 768 + 512 + h * 32 + c];
  }
  bs[tid] = (1.0f - mask[n * 64 + tid]) * -1e9f;
  __syncthreads();
  float acc[8][8] = {};
  for (int c = 0; c < 32; c++) {
    float4 ax = *(float4*)&Qt[c][ty * 8];
    float4 ay = *(float4*)&Qt[c][ty * 8 + 4];
    float4 bx = *(float4*)&Kt[c][tx * 8];
    float4 by = *(float4*)&Kt[c][tx * 8 + 4];
    float a8[8] = {ax.x, ax.y, ax.z, ax.w, ay.x, ay.y, ay.z, ay.w};
    float b8[8] = {bx.x, bx.y, bx.z, bx.w, by.x, by.y, by.z, by.w};
#pragma unroll
    for (int i = 0; i < 8; i++)
#pragma unroll
      for (int j = 0; j < 8; j++) acc[i][j] = fmaf(a8[i], b8[j], acc[i][j]);
  }
  __syncthreads();
  const float scale = 0.17677669529663687f;
#pragma unroll
  for (int i = 0; i < 8; i++) {
    float s[8];
    float mx = -3.0e38f;
#pragma unroll
    for (int j = 0; j < 8; j++) { s[j] = acc[i][j] * scale + bs[tx * 8 + j]; mx = fmaxf(mx, s[j]); }
#pragma unroll
    for (int off = 1; off < 8; off <<= 1) mx = fmaxf(mx, __shfl_xor(mx, off));
    float sum = 0.0f;
#pragma unroll
    for (int j = 0; j < 8; j++) { s[j] = expf(s[j] - mx); sum += s[j]; }
#pragma unroll
    for (int off = 1; off < 8; off <<= 1) sum += __shfl_xor(sum, off);
    float inv = 1.0f / sum;
#pragma unroll
    for (int j = 0; j < 8; j++) Pt[tx * 8 + j][ty * 8 + i] = s[j] * inv;
  }
  __syncthreads();
  float o[8][4] = {};
  for (int j = 0; j < 64; j++) {
    float4 px = *(float4*)&Pt[j][ty * 8];
    float4 py = *(float4*)&Pt[j][ty * 8 + 4];
    float4 v  = *(float4*)&Vs[j][tx * 4];
    float p8[8] = {px.x, px.y, px.z, px.w, py.x, py.y, py.z, py.w};
#pragma unroll
    for (int i = 0; i < 8; i++) {
      o[i][0] = fmaf(p8[i], v.x, o[i][0]);
      o[i][1] = fmaf(p8[i], v.y, o[i][1]);
      o[i][2] = fmaf(p8[i], v.z, o[i][2]);
      o[i][3] = fmaf(p8[i], v.w, o[i][3]);
    }
  }
#pragma unroll
  for (int i = 0; i < 8; i++) {
    size_t base_o = (size_t)(nl * 64 + ty * 8 + i) * 256 + h * 32 + tx * 4;
#pragma unroll
    for (int c = 0; c < 4; c++) {
      unsigned short hi, lo; bfsplit(o[i][c], hi, lo);
      AThi[base_o + c] = hi; ATlo[base_o + c] = lo;
    }
  }
}

// ---------- LayerNorm wave-per-row (mamba): o = LN(a)*g+beta + b; + split ------
__global__ __launch_bounds__(256) void ln_res_kernel(
    const float* __restrict__ a, const float* __restrict__ b,
    const float* __restrict__ g, const float* __restrict__ beta,
    float* __restrict__ o, unsigned short* __restrict__ ohi, unsigned short* __restrict__ olo,
    int Wd)
{
  int wave = threadIdx.x >> 6;
  int lane = threadIdx.x & 63;
  int row = blockIdx.x * 4 + wave;
  int P = Wd >> 6;
  const float* ar = a + (size_t)row * Wd;
  const float* br = b + (size_t)row * Wd;
  float v[8];
  float s = 0.0f;
  for (int i = 0; i < P; i++) { float x = ar[lane + i * 64]; v[i] = x; s += x; }
#pragma unroll
  for (int off = 32; off; off >>= 1) s += __shfl_xor(s, off);
  float mean = s / Wd;
  float vs = 0.0f;
  for (int i = 0; i < P; i++) { float d = v[i] - mean; vs += d * d; }
#pragma unroll
  for (int off = 32; off; off >>= 1) vs += __shfl_xor(vs, off);
  float rstd = rsqrtf(vs / Wd + 1e-5f);
  for (int i = 0; i < P; i++) {
    int col = lane + i * 64;
    float t = (v[i] - mean) * rstd * g[col] + beta[col] + br[col];
    size_t idx = (size_t)row * Wd + col;
    o[idx] = t;
    unsigned short hi, lo; bfsplit(t, hi, lo);
    ohi[idx] = hi; olo[idx] = lo;
  }
}

// ------------- masked mean over bars (reads hi/lo X) ---------------------------
__global__ __launch_bounds__(256) void mean_kernel(
    const unsigned short* __restrict__ Xhi, const unsigned short* __restrict__ Xlo,
    const float* __restrict__ mask, float* __restrict__ FE, int n0)
{
  int n = blockIdx.x;
  int c = threadIdx.x;
  float s = 0.0f, ms = 0.0f;
  for (int bar = 0; bar < 64; bar++) {
    float mk = mask[(n0 + n) * 64 + bar];
    size_t idx = (size_t)(n * 64 + bar) * 256 + c;
    s = fmaf(bf2f(Xhi[idx]) + bf2f(Xlo[idx]), mk, s);
    ms += mk;
  }
  FE[(n0 + n) * 256 + c] = s / fmaxf(ms, 1.0f);
}

// ---------------- mamba conv (4-tap causal) + silu ----------------
__global__ __launch_bounds__(256) void conv_kernel(
    const float* __restrict__ XZ, const float* __restrict__ w,
    const float* __restrict__ b, float* __restrict__ XC)
{
  int idx = blockIdx.x * 256 + threadIdx.x;
  int t = idx >> 10, c = idx & 1023;
  float acc = b[c];
  const float* wc = w + c * 4;
#pragma unroll
  for (int k = 0; k < 4; k++) {
    int tt = t + k - 3;
    if (tt >= 0) acc = fmaf(XZ[(size_t)tt * 2048 + c], wc[k], acc);
  }
  XC[idx] = acc / (1.0f + expf(-acc));
}

// ---------------- chunked scan (32 chunks x 32 steps) ----------------
#define NCH 32
#define CLEN 32

__global__ __launch_bounds__(256) void scan1_kernel(
    const float* __restrict__ DT, const float* __restrict__ XC,
    const float* __restrict__ XDBL, const float* __restrict__ Alog,
    float* __restrict__ HEND, float* __restrict__ PPR)
{
  int j = blockIdx.x >> 2;
  int c = (blockIdx.x & 3) * 256 + threadIdx.x;
  int t0 = j * CLEN;
  __shared__ float Bs[CLEN][16];
  for (int i = threadIdx.x; i < CLEN * 16; i += 256) {
    int r = i >> 4, s = i & 15;
    Bs[r][s] = XDBL[(t0 + r) * 64 + 32 + s];
  }
  float A[16], h[16], Pp[16];
#pragma unroll
  for (int s = 0; s < 16; s++) {
    A[s] = -expf(Alog[c * 16 + s]);
    h[s] = 0.0f; Pp[s] = 1.0f;
  }
  __syncthreads();
  for (int tt = 0; tt < CLEN; tt++) {
    int t = t0 + tt;
    float dtv = DT[(size_t)t * 1024 + c];
    float u = dtv * XC[(size_t)t * 1024 + c];
#pragma unroll
    for (int s = 0; s < 16; s++) {
      float e = expf(dtv * A[s]);
      h[s] = fmaf(h[s], e, u * Bs[tt][s]);
      Pp[s] *= e;
    }
  }
#pragma unroll
  for (int s = 0; s < 16; s++) {
    HEND[(size_t)(j * 1024 + c) * 16 + s] = h[s];
    PPR [(size_t)(j * 1024 + c) * 16 + s] = Pp[s];
  }
}

__global__ __launch_bounds__(256) void scan2_kernel(
    const float* __restrict__ HEND, const float* __restrict__ PPR, float* __restrict__ CIN)
{
  int id = blockIdx.x * 256 + threadIdx.x;
  float carry = 0.0f;
  for (int j = 0; j < NCH; j++) {
    CIN[j * 16384 + id] = carry;
    carry = fmaf(PPR[j * 16384 + id], carry, HEND[j * 16384 + id]);
  }
}

__global__ __launch_bounds__(256) void scan3_kernel(
    const float* __restrict__ DT, const float* __restrict__ XC,
    const float* __restrict__ XDBL, const float* __restrict__ Alog,
    const float* __restrict__ CIN, const float* __restrict__ mD,
    const float* __restrict__ XZ, float* __restrict__ Y)
{
  int j = blockIdx.x >> 2;
  int c = (blockIdx.x & 3) * 256 + threadIdx.x;
  int t0 = j * CLEN;
  __shared__ float Bs[CLEN][16], Cs[CLEN][16];
  for (int i = threadIdx.x; i < CLEN * 16; i += 256) {
    int r = i >> 4, s = i & 15;
    Bs[r][s] = XDBL[(t0 + r) * 64 + 32 + s];
    Cs[r][s] = XDBL[(t0 + r) * 64 + 48 + s];
  }
  float A[16], h[16];
#pragma unroll
  for (int s = 0; s < 16; s++) {
    A[s] = -expf(Alog[c * 16 + s]);
    h[s] = CIN[(size_t)(j * 1024 + c) * 16 + s];
  }
  float dval = mD[c];
  __syncthreads();
  for (int tt = 0; tt < CLEN; tt++) {
    int t = t0 + tt;
    float dtv = DT[(size_t)t * 1024 + c];
    float xcv = XC[(size_t)t * 1024 + c];
    float u = dtv * xcv;
    float y = 0.0f;
#pragma unroll
    for (int s = 0; s < 16; s++) {
      float e = expf(dtv * A[s]);
      h[s] = fmaf(h[s], e, u * Bs[tt][s]);
      y = fmaf(h[s], Cs[tt][s], y);
    }
    float z = XZ[(size_t)t * 2048 + 1024 + c];
    float sz = z / (1.0f + expf(-z));
    Y[(size_t)t * 1024 + c] = (y + dval * xcv) * sz;
  }
}

// ---------------- pooling + head ----------------
__global__ __launch_bounds__(1024) void pool1_kernel(
    const float* __restrict__ XM, const float* __restrict__ pw,
    const float* __restrict__ pb, float* __restrict__ PW)
{
  int t = threadIdx.x;
  float s = pb[0];
  for (int i = 0; i < 512; i++) s = fmaf(XM[(size_t)t * 512 + i], pw[i], s);
  __shared__ float red[1024];
  red[t] = s;
  __syncthreads();
  for (int off = 512; off > 0; off >>= 1) {
    if (t < off) red[t] = fmaxf(red[t], red[t + off]);
    __syncthreads();
  }
  float mx = red[0];
  __syncthreads();
  float e = expf(s - mx);
  red[t] = e;
  __syncthreads();
  for (int off = 512; off > 0; off >>= 1) {
    if (t < off) red[t] = red[t] + red[t + off];
    __syncthreads();
  }
  PW[t] = e / red[0];
}

__global__ __launch_bounds__(256) void pool2_kernel(
    const float* __restrict__ XM, const float* __restrict__ PW, float* __restrict__ HP)
{
  int hcol = blockIdx.x * 256 + threadIdx.x;
  float s = 0.0f;
  for (int tn = 0; tn < 1024; tn++) s = fmaf(PW[tn], XM[(size_t)tn * 512 + hcol], s);
  HP[hcol] = s;
}

__device__ __forceinline__ float blk_reduce_sum_128(float v, float* red){
  int t = threadIdx.x;
#pragma unroll
  for (int off = 32; off; off >>= 1) v += __shfl_xor(v, off);
  __syncthreads();
  if ((t & 63) == 0) red[t >> 6] = v;
  __syncthreads();
  return red[0] + red[1];
}

__global__ __launch_bounds__(128) void head_kernel(
    const float* __restrict__ HP, const float* __restrict__ h1w, const float* __restrict__ h1b,
    const float* __restrict__ g1, const float* __restrict__ be1,
    const float* __restrict__ h2w, const float* __restrict__ h2b,
    const float* __restrict__ g2, const float* __restrict__ be2,
    const float* __restrict__ h3w, const float* __restrict__ h3b,
    float* __restrict__ out)
{
  __shared__ float t1[128];
  __shared__ float red[2];
  int i = threadIdx.x;
  float s = h1b[i];
  for (int k = 0; k < 512; k++) s = fmaf(HP[k], h1w[k * 128 + i], s);
  float mean = blk_reduce_sum_128(s, red) * (1.0f / 128.0f);
  float d = s - mean;
  float var = blk_reduce_sum_128(d * d, red) * (1.0f / 128.0f);
  float x1 = d * rsqrtf(var + 1e-5f) * g1[i] + be1[i];
  x1 = 0.5f * x1 * (1.0f + erff(x1 * 0.70710678118654752f));
  t1[i] = x1;
  __syncthreads();
  s = h2b[i];
  for (int k = 0; k < 128; k++) s = fmaf(t1[k], h2w[k * 128 + i], s);
  mean = blk_reduce_sum_128(s, red) * (1.0f / 128.0f);
  d = s - mean;
  var = blk_reduce_sum_128(d * d, red) * (1.0f / 128.0f);
  float x2 = d * rsqrtf(var + 1e-5f) * g2[i] + be2[i];
  x2 = 0.5f * x2 * (1.0f + erff(x2 * 0.70710678118654752f));
  float tot = blk_reduce_sum_128(x2 * h3w[i], red);
  if (i == 0) out[0] = tot + h3b[0];
}

__global__ __launch_bounds__(256) void copyx_kernel(const float* __restrict__ XM, float* __restrict__ out){
  int i = blockIdx.x * 256 + threadIdx.x;
  out[1 + i] = XM[i];
}

// ---------------- launch ----------------
extern "C" void kernel_launch(void* const* d_in, const int* in_sizes, int n_in,
                              void* d_out, int out_size, void* d_ws, size_t ws_size,
                              hipStream_t stream)
{
  const float* frames   = (const float*)d_in[0];
  const float* fmask    = (const float*)d_in[1];
  const float* in_w     = (const float*)d_in[2];
  const float* in_b     = (const float*)d_in[3];
  const float* pos_emb  = (const float*)d_in[4];
  const float* qkv_w    = (const float*)d_in[5];
  const float* qkv_b    = (const float*)d_in[6];
  const float* ao_w     = (const float*)d_in[7];
  const float* ao_b     = (const float*)d_in[8];
  const float* ln1_g    = (const float*)d_in[9];
  const float* ln1_b    = (const float*)d_in[10];
  const float* ffn_w1   = (const float*)d_in[11];
  const float* ffn_b1   = (const float*)d_in[12];
  const float* ffn_w2   = (const float*)d_in[13];
  const float* ffn_b2   = (const float*)d_in[14];
  const float* ln2_g    = (const float*)d_in[15];
  const float* ln2_b    = (const float*)d_in[16];
  const float* proj_w   = (const float*)d_in[17];
  const float* proj_b   = (const float*)d_in[18];
  const float* m_in_w   = (const float*)d_in[19];
  const float* m_conv_w = (const float*)d_in[20];
  const float* m_conv_b = (const float*)d_in[21];
  const float* m_xproj_w= (const float*)d_in[22];
  const float* m_dt_w   = (const float*)d_in[23];
  const float* m_dt_b   = (const float*)d_in[24];
  const float* m_Alog   = (const float*)d_in[25];
  const float* m_D      = (const float*)d_in[26];
  const float* m_out_w  = (const float*)d_in[27];
  const float* m_ln_g   = (const float*)d_in[28];
  const float* m_ln_b   = (const float*)d_in[29];
  const float* pool_w   = (const float*)d_in[30];
  const float* pool_b   = (const float*)d_in[31];
  const float* h1_w     = (const float*)d_in[32];
  const float* h1_b     = (const float*)d_in[33];
  const float* hg1      = (const float*)d_in[34];
  const float* hb1      = (const float*)d_in[35];
  const float* h2_w     = (const float*)d_in[36];
  const float* h2_b     = (const float*)d_in[37];
  const float* hg2      = (const float*)d_in[38];
  const float* hb2      = (const float*)d_in[39];
  const float* h3_w     = (const float*)d_in[40];
  const float* h3_b     = (const float*)d_in[41];
  float* out = (float*)d_out;

  // ---- workspace layout (floats), total 25,431,040 = 101.7 MB ----
  float* ws = (float*)d_ws;
  float* B  = ws;
  float* QF = B;                                       // 12,582,912 floats
  unsigned short* AThi = (unsigned short*)(B + 12582912);  // 4,194,304 shorts
  unsigned short* ATlo = AThi + 4194304;
  unsigned short* MIDhi = (unsigned short*)B;              // 16,777,216 shorts
  unsigned short* MIDlo = MIDhi + 16777216;

  unsigned short* Xhi = (unsigned short*)(ws + 16777216);  // 4,194,304 shorts
  unsigned short* Xlo = Xhi + 4194304;

  unsigned short* Wqkv_hi = (unsigned short*)(ws + 20971520); // 786,432
  unsigned short* Wqkv_lo = Wqkv_hi + 786432;
  unsigned short* Wao_hi  = Wqkv_lo + 786432;    // 262,144
  unsigned short* Wao_lo  = Wao_hi + 262144;
  unsigned short* Wf1_hi  = Wao_lo + 262144;     // 1,048,576
  unsigned short* Wf1_lo  = Wf1_hi + 1048576;
  unsigned short* Wf2_hi  = Wf1_lo + 1048576;    // 1,048,576
  unsigned short* Wf2_lo  = Wf2_hi + 1048576;    // ends at ws + 24,117,248 floats

  float* FE = ws + 24117248;         //   262,144
  float* XM = FE + 262144;           //   524,288
  float* PW = XM + 524288;           //     2,048
  float* HP = PW + 2048;             //     1,024  (ends 24,906,752)
  unsigned short* XMhi = (unsigned short*)(ws + 24906752); // 524,288 shorts
  unsigned short* XMlo = XMhi + 524288;                    // region 524,288 floats -> 25,431,040

  // mamba aliases overlay B (scan buffers end at 7,405,568)
  float* XZ   = B;                 // 2,097,152 (1024x2048)
  float* XC   = B + 2097152;       // 1,048,576
  float* DT   = B + 3145728;       // 1,048,576
  float* XDBL = B + 4194304;       //    65,536
  float* Y    = B + 4259840;       // 1,048,576
  float* TMP  = B + 5308416;       //   524,288
  float* HEND = B + 5832704;       //   524,288
  float* PPR  = B + 6356992;       //   524,288
  float* CIN  = B + 6881280;       //   524,288  (ends 7,405,568)
  unsigned short* WINhi = (unsigned short*)(B + 7500000);  // 1,048,576 shorts (512x2048)
  unsigned short* WINlo = WINhi + 1048576;                 // ends B+8,548,576 fl < 16.78M

  // ---- weight prep: 4 batched launches (z = layer) ----
  wsplit_kernel<<<dim3(24,8,4),256,0,stream>>>(qkv_w, Wqkv_hi, Wqkv_lo, 256, 768, 196608, 196608);
  wsplit_kernel<<<dim3(8,8,4),256,0,stream>>>(ao_w, Wao_hi, Wao_lo, 256, 256, 65536, 65536);
  wsplit_kernel<<<dim3(32,8,4),256,0,stream>>>(ffn_w1, Wf1_hi, Wf1_lo, 256, 1024, 262144, 262144);
  wsplit_kernel<<<dim3(8,32,4),256,0,stream>>>(ffn_w2, Wf2_hi, Wf2_lo, 1024, 256, 262144, 262144);

  // ---- encoder: 4 chunks of 256 sequences (16384 rows) ----
  for (int ch = 0; ch < 4; ch++) {
    int n0 = ch * 256;
    const float* fch = frames + (size_t)n0 * 64 * 32;
    gemm128_kernel<ACT_NONE,1,1><<<dim3(2,128),256,0,stream>>>(
        fch, in_w, in_b, pos_emb, QF, Xhi, Xlo, 32, 32, 256, 256);
    for (int l = 0; l < 4; l++) {
      // QKV: grid m-major (128 m-blocks x 6 n-blocks)
      gemm_bf16x2_kernel<ACT_NONE,0><<<dim3(128,6),256,0,stream>>>(
          Xhi, Xlo, Wqkv_hi + l*196608, Wqkv_lo + l*196608, qkv_b + l*768,
          QF, nullptr, nullptr, 256, 256, 256, 768);
      attn_fused_kernel<<<2048,64,0,stream>>>(QF, fmask, AThi, ATlo, n0);
      gemm_ln_kernel<<<256,512,0,stream>>>(
          AThi, ATlo, Wao_hi + l*65536, Wao_lo + l*65536, ao_b + l*256,
          ln1_g + l*256, ln1_b + l*256, Xhi, Xlo, 256, 256, 256);
      // FFN1: grid m-major (128 x 8)
      gemm_bf16x2_kernel<ACT_GELU,2><<<dim3(128,8),256,0,stream>>>(
          Xhi, Xlo, Wf1_hi + l*262144, Wf1_lo + l*262144, ffn_b1 + l*1024,
          nullptr, MIDhi, MIDlo, 256, 256, 256, 1024);
      gemm_ln_kernel<<<256,512,0,stream>>>(
          MIDhi, MIDlo, Wf2_hi + l*262144, Wf2_lo + l*262144, ffn_b2 + l*256,
          ln2_g + l*256, ln2_b + l*256, Xhi, Xlo, 1024, 1024, 1024);
    }
    mean_kernel<<<256,256,0,stream>>>(Xhi, Xlo, fmask, FE, n0);
  }

  // proj: fp32 gemm64 with split write (XM + XMhi/XMlo)
  gemm64_kernel<ACT_NONE,1><<<dim3(8,16),256,0,stream>>>(
      FE, proj_w, proj_b, XM, XMhi, XMlo, 256, 256, 512, 512);

  for (int l = 0; l < 8; l++) {
    // in-proj: split weights on the fly, then MFMA (m-major grid 8x16)
    wsplit_kernel<<<dim3(64,16,1),256,0,stream>>>(
        m_in_w + (size_t)l*512*2048, WINhi, WINlo, 512, 2048, 0, 0);
    gemm_bf16x2_kernel<ACT_NONE,0><<<dim3(8,16),256,0,stream>>>(
        XMhi, XMlo, WINhi, WINlo, nullptr, XZ, nullptr, nullptr, 512, 512, 512, 2048);
    conv_kernel<<<4096,256,0,stream>>>(XZ, m_conv_w + l*1024*4, m_conv_b + l*1024, XC);
    gemm64_kernel<ACT_NONE,0><<<dim3(1,16),256,0,stream>>>(
        XC, m_xproj_w + (size_t)l*1024*64, nullptr, XDBL, nullptr, nullptr, 1024, 1024, 64, 64);
    gemm64_kernel<ACT_SOFTPLUS,0><<<dim3(16,16),256,0,stream>>>(
        XDBL, m_dt_w + (size_t)l*32*1024, m_dt_b + l*1024, DT, nullptr, nullptr, 32, 64, 1024, 1024);
    scan1_kernel<<<128,256,0,stream>>>(DT, XC, XDBL, m_Alog + l*16384, HEND, PPR);
    scan2_kernel<<<64,256,0,stream>>>(HEND, PPR, CIN);
    scan3_kernel<<<128,256,0,stream>>>(DT, XC, XDBL, m_Alog + l*16384, CIN, m_D + l*1024, XZ, Y);
    gemm64_kernel<ACT_NONE,0><<<dim3(8,16),256,0,stream>>>(
        Y, m_out_w + (size_t)l*1024*512, nullptr, TMP, nullptr, nullptr, 1024, 1024, 512, 512);
    ln_res_kernel<<<256,256,0,stream>>>(TMP, XM, m_ln_g + l*512, m_ln_b + l*512, XM, XMhi, XMlo, 512);
  }

  pool1_kernel<<<1,1024,0,stream>>>(XM, pool_w, pool_b, PW);
  pool2_kernel<<<2,256,0,stream>>>(XM, PW, HP);
  head_kernel<<<1,128,0,stream>>>(HP, h1_w, h1_b, hg1, hb1, h2_w, h2_b, hg2, hb2, h3_w, h3_b, out);
  copyx_kernel<<<2048,256,0,stream>>>(XM, out);
}